// Round 7
// baseline (348.109 us; speedup 1.0000x reference)
//
#include <hip/hip_runtime.h>

typedef _Float16 f16;
typedef _Float16 f16x8 __attribute__((ext_vector_type(8)));
typedef float f32x4 __attribute__((ext_vector_type(4)));

// ---- workspace layout (bytes) ----
#define WS_EWIH 4194304                // enc Wih f16 [384][32] (k>=29 zero)
#define WS_EWHH 4218880                // enc Whh f16 [384][128]
#define WS_DWC  4317184                // dec combined f16 [512][128]
#define WS_DWHH 4448256                // dec Whh f16 [384][128]
#define WS_BIAS 4546560                // f32[1024]
#define WS_W1F  4550656                // conv1 B-frags f16 [9][16][32]
#define WS_W2F  4559872                // conv2 B-frags f16 [2][32][32]
#define WS_FCWF 4563968                // fc weights f16 [128][128]

static __device__ __forceinline__ f32x4 mfma16(f16x8 a, f16x8 b, f32x4 c) {
    return __builtin_amdgcn_mfma_f32_16x16x32_f16(a, b, c, 0, 0, 0);
}
static __device__ __forceinline__ float fexp2n(float x) {   // 2^(-x*log2e) = e^-x
    return __builtin_amdgcn_exp2f(x * -1.4426950408889634f);
}

// ---------------- prep: f32 -> f16 packs (raw values; NO scale folding) ----
__global__ void k_prep(const float* __restrict__ eWih, const float* __restrict__ eWhh,
                       const float* __restrict__ ebih, const float* __restrict__ ebhh,
                       const float* __restrict__ dWih, const float* __restrict__ dWhh,
                       const float* __restrict__ dbih, const float* __restrict__ dbhh,
                       const float* __restrict__ w1, const float* __restrict__ w2,
                       const float* __restrict__ fcw,
                       char* __restrict__ ws)
{
    f16* ewih = (f16*)(ws + WS_EWIH);
    f16* ewhh = (f16*)(ws + WS_EWHH);
    f16* dwc  = (f16*)(ws + WS_DWC);
    f16* dwhh = (f16*)(ws + WS_DWHH);
    float* bias = (float*)(ws + WS_BIAS);
    f16* w1f = (f16*)(ws + WS_W1F);
    f16* w2f = (f16*)(ws + WS_W2F);
    f16* fcwf = (f16*)(ws + WS_FCWF);
    const int total = 12288 + 49152 + 65536 + 49152 + 1024 + 4608 + 2048 + 16384;
    for (int i = blockIdx.x * 256 + threadIdx.x; i < total; i += gridDim.x * 256) {
        int j = i;
        if (j < 12288) { int g = j >> 5, k = j & 31;
            ewih[j] = (f16)((k < 29) ? eWih[g * 29 + k] : 0.0f); continue; }
        j -= 12288;
        if (j < 49152) { ewhh[j] = (f16)eWhh[j]; continue; }
        j -= 49152;
        if (j < 65536) { int row = j >> 7, k = j & 127; float v;
            if (row < 256)      v = dWih[row * 128 + k] + dWhh[row * 128 + k];
            else if (row < 384) v = dWih[row * 128 + k];
            else                v = dWhh[(row - 128) * 128 + k];
            dwc[j] = (f16)v; continue; }
        j -= 65536;
        if (j < 49152) { dwhh[j] = (f16)dWhh[j]; continue; }
        j -= 49152;
        if (j < 1024) {
            if (j < 256)        bias[j] = ebih[j] + ebhh[j];
            else if (j < 384)   bias[j] = ebih[j];
            else if (j < 512)   bias[j] = ebhh[j - 128];
            else if (j < 768)   bias[j] = dbih[j - 512] + dbhh[j - 512];
            else if (j < 896)   bias[j] = dbih[j - 512];
            else                bias[j] = dbhh[j - 640];
            continue; }
        j -= 1024;
        if (j < 4608) {   // w1f[kk][co][k]: w1 (16,27,3,3) OIHW; k>=27 -> 0
            int kk = j >> 9, rem = j & 511, co = rem >> 5, k = rem & 31;
            w1f[j] = (f16)((k < 27) ? w1[co * 243 + k * 9 + kk] : 0.0f); continue; }
        j -= 4608;
        if (j < 2048) {   // w2f[s][co][k]
            int s = j >> 10, rem = j & 1023, co = rem >> 5, k = rem & 31;
            int kk2 = 2 * s + (k >= 16), ci = k & 15;
            w2f[j] = (f16)w2[co * 64 + ci * 4 + kk2]; continue; }
        j -= 2048;
        fcwf[j] = (f16)fcw[j];
    }
}

// -------- fused CNN + GRU + heads: 512 threads, 32 rows/block, grid 256 --------
// STRUCTURAL L2-traffic halving: 1 block/CU (grid 256 = 256 CUs) processing
// 32 batch rows as two 16-row tiles (A/B) per wave. Each weight fragment is
// loaded once per step and feeds the MFMAs of BOTH tiles — so even with the
// allocator sinking weight loads into the recurrence loop (proven behavior:
// VGPR=64 across R2/R5 regardless of budget attributes), per-CU weight
// re-stream from L2 halves: ~220 KB/step -> ~110 KB/step (~3900 -> ~1950
// cyc/step of L2 BW at ~1.9 KB/cyc/XCD). Per-element math order is identical
// to the baseline (same MFMA shapes/k-order/gate math) -> bit-identical output.
__global__ __launch_bounds__(512, 2) void k_gru(
    const float* __restrict__ cin,
    const float* __restrict__ lin,
    const float* __restrict__ b1, const float* __restrict__ b2,
    const float* __restrict__ fcb,
    const char* __restrict__ ws,
    const float* __restrict__ dis_w, const float* __restrict__ dis_b,
    const float* __restrict__ value_w, const float* __restrict__ value_b,
    float* __restrict__ out)
{
    __shared__ __align__(16) char smem[55296];
    f16 (*h_s)[2][16][136]  = (f16(*)[2][16][136])(smem);          // [buf][tile] 17408 B
    f16 (*x_s)[2][16][32]   = (f16(*)[2][16][32])(smem + 17408);   // [buf][tile] 4096 B
    float (*pn_s)[264]      = (float(*)[264])(smem + 21504);       // [32][264] 33792 B
    f16 (*a1f)[9][24]       = (f16(*)[9][24])(smem);               // 6912 B, alias (CNN only)
    f16 (*vf)[136]          = (f16(*)[136])(smem + 8704);          // 4352 B, alias (CNN only)

    const int tid = threadIdx.x;
    const int wv = tid >> 6;
    const int lane = tid & 63;
    const int nl = lane & 15;
    const int quad = lane >> 4;
    const int j0 = wv * 16;
    const int row0 = blockIdx.x * 32;

    const f16* ewih = (const f16*)(ws + WS_EWIH);
    const f16* ewhh = (const f16*)(ws + WS_EWHH);
    const f16* dwc  = (const f16*)(ws + WS_DWC);
    const f16* dwhh = (const f16*)(ws + WS_DWHH);
    const float* bias = (const float*)(ws + WS_BIAS);
    const f16* w1f = (const f16*)(ws + WS_W1F);
    const f16* w2f = (const f16*)(ws + WS_W2F);
    const f16* fcwf = (const f16*)(ws + WS_FCWF);

    // ============ CNN prologue: 32 images as two groups of 16 ============
    for (int g = 0; g < 2; g++) {
        // conv1: 9 output positions over 8 waves
        const float* imgp = cin + (size_t)(row0 + g * 16 + nl) * 1728 + quad * 8;
        float b1v = b1[nl];
        for (int p = wv; p < 9; p += 8) {
            int oy = p / 3, ox = p % 3;
            f32x4 acc = {b1v, b1v, b1v, b1v};
            #pragma unroll
            for (int kk = 0; kk < 9; kk++) {
                f16x8 bw = *(const f16x8*)(w1f + (kk * 16 + nl) * 32 + quad * 8);
                int pix = (2 * oy + kk / 3) * 8 + (2 * ox + kk % 3);
                const float* s = imgp + pix * 27;
                f16x8 a;
                #pragma unroll
                for (int jj = 0; jj < 8; jj++) a[jj] = (f16)s[jj];
                acc = mfma16(a, bw, acc);
            }
            #pragma unroll
            for (int r = 0; r < 4; r++)
                a1f[quad * 4 + r][p][nl] = (f16)fmaxf(acc[r], 0.0f);
        }
        __syncthreads();
        // conv2: 4 positions x 2 nt = 8 units -> one per wave
        {
            int pos = wv >> 1, nt = wv & 1;
            int y = pos >> 1, x = pos & 1;
            float bv = b2[nt * 16 + nl];
            f32x4 acc = {bv, bv, bv, bv};
            #pragma unroll
            for (int s = 0; s < 2; s++) {
                int kk2 = 2 * s + (quad >> 1);
                int pos1 = (y + (kk2 >> 1)) * 3 + (x + (kk2 & 1));
                f16x8 a = *(const f16x8*)(&a1f[nl][pos1][(quad & 1) * 8]);
                f16x8 b = *(const f16x8*)(w2f + ((size_t)s * 32 + nt * 16 + nl) * 32 + quad * 8);
                acc = mfma16(a, b, acc);
            }
            #pragma unroll
            for (int r = 0; r < 4; r++)
                vf[quad * 4 + r][(nt * 16 + nl) * 4 + (y * 2 + x)] = (f16)fmaxf(acc[r], 0.0f);
        }
        __syncthreads();
        // fc 128->128: wave wv -> outputs wv*16..wv*16+15 into pn_s rows of this group
        {
            int o = wv * 16 + nl;
            float bv = fcb[o];
            f32x4 acc = {bv, bv, bv, bv};
            #pragma unroll
            for (int kt = 0; kt < 4; kt++) {
                f16x8 a = *(const f16x8*)(&vf[nl][kt * 32 + quad * 8]);
                f16x8 b = *(const f16x8*)(fcwf + o * 128 + kt * 32 + quad * 8);
                acc = mfma16(a, b, acc);
            }
            #pragma unroll
            for (int r = 0; r < 4; r++)
                pn_s[g * 16 + quad * 4 + r][o] = fmaxf(acc[r], 0.0f);
        }
        __syncthreads();   // a1f/vf dead for this group before next overwrites
    }

    for (int i = tid; i < 2 * 2 * 16 * 136; i += 512) ((f16*)h_s)[i] = (f16)0.0f;

    const int rsw = (nl & 8) ? 16 : 0;    // read-side swizzle (row = nl)
    const int wrow = quad * 4;            // write rows wrow..wrow+3
    const int wsw = (quad >= 2) ? 16 : 0; // write-side swizzle (rows 8-15)
    const int wcol = (j0 + nl + wsw) & 127;
    const int c0 = (quad * 8 + rsw) & 127;
    const int c1 = (32 + quad * 8 + rsw) & 127;
    const int c2 = (64 + quad * 8 + rsw) & 127;
    const int c3 = (96 + quad * 8 + rsw) & 127;

    float hoA[4], hoB[4];
    #pragma unroll
    for (int r = 0; r < 4; r++) { hoA[r] = 0.0f; hoB[r] = 0.0f; }

    const int xr = tid >> 5, xc = tid & 31;   // x staging: 16 rows x 32 cols per tile
    const bool xok = (xc < 29);
    const size_t lin_baseA = (size_t)(row0 + xr) * 1856 + xc;
    const size_t lin_baseB = (size_t)(row0 + 16 + xr) * 1856 + xc;

// GATES takes the destination buffer (OB) and tile (TI) explicitly —
// macro parameters do not propagate into nested macro bodies (R6 lesson).
#define GATES(AR, AZ, AXN, AHN, HO, OB, TI, BR, BZ, BXN, BHN)                        \
        _Pragma("unroll")                                                            \
        for (int r = 0; r < 4; r++) {                                                \
            float ea = fexp2n((AR)[r]), eb = fexp2n((AZ)[r]);                        \
            float s1 = 1.0f + ea, s2 = 1.0f + eb;                                    \
            float R = __builtin_amdgcn_rcpf(s1 * s2);                                \
            float rg = s2 * R, zg = s1 * R;                                          \
            float ec = fexp2n(2.0f * ((AXN)[r] + rg * (AHN)[r]));                    \
            float ng = (1.0f - ec) * __builtin_amdgcn_rcpf(1.0f + ec);               \
            float h = ng + zg * ((HO)[r] - ng);                                      \
            (HO)[r] = h;                                                             \
            h_s[OB][TI][wrow + r][wcol] = (f16)h;                                    \
        }

    // ================= encoder =================
    {
        float eb_r, eb_z, eb_xn, eb_hn;
        { int c = j0 + nl;
          eb_r = bias[c]; eb_z = bias[128 + c]; eb_xn = bias[256 + c]; eb_hn = bias[384 + c]; }
        f16x8 we_r[4], we_z[4], we_hn[4], we_xr, we_xz, we_xn;
        { int gr = j0 + nl;
          #pragma unroll
          for (int kt = 0; kt < 4; kt++) {
              we_r[kt]  = *(const f16x8*)(ewhh + gr * 128 + kt * 32 + quad * 8);
              we_z[kt]  = *(const f16x8*)(ewhh + (128 + gr) * 128 + kt * 32 + quad * 8);
              we_hn[kt] = *(const f16x8*)(ewhh + (256 + gr) * 128 + kt * 32 + quad * 8);
          }
          we_xr = *(const f16x8*)(ewih + gr * 32 + quad * 8);
          we_xz = *(const f16x8*)(ewih + (128 + gr) * 32 + quad * 8);
          we_xn = *(const f16x8*)(ewih + (256 + gr) * 32 + quad * 8);
        }

        float xvA = xok ? lin[lin_baseA] : 0.0f;
        float xvB = xok ? lin[lin_baseB] : 0.0f;

#define ENC_STEP(BUF, OBUF, TN)                                                      \
        do {                                                                         \
            x_s[BUF][0][xr][xc] = (f16)xvA;                                          \
            x_s[BUF][1][xr][xc] = (f16)xvB;                                          \
            __syncthreads();                                                         \
            f16x8 axA = *(const f16x8*)(&x_s[BUF][0][nl][quad * 8]);                 \
            f16x8 axB = *(const f16x8*)(&x_s[BUF][1][nl][quad * 8]);                 \
            f16x8 aA0 = *(const f16x8*)(&h_s[BUF][0][nl][c0]);                       \
            f16x8 aA1 = *(const f16x8*)(&h_s[BUF][0][nl][c1]);                       \
            f16x8 aA2 = *(const f16x8*)(&h_s[BUF][0][nl][c2]);                       \
            f16x8 aA3 = *(const f16x8*)(&h_s[BUF][0][nl][c3]);                       \
            f16x8 aB0 = *(const f16x8*)(&h_s[BUF][1][nl][c0]);                       \
            f16x8 aB1 = *(const f16x8*)(&h_s[BUF][1][nl][c1]);                       \
            f16x8 aB2 = *(const f16x8*)(&h_s[BUF][1][nl][c2]);                       \
            f16x8 aB3 = *(const f16x8*)(&h_s[BUF][1][nl][c3]);                       \
            if ((TN) < 64) {                                                         \
                xvA = xok ? lin[lin_baseA + (TN) * 29] : 0.0f;                       \
                xvB = xok ? lin[lin_baseB + (TN) * 29] : 0.0f;                       \
            }                                                                        \
            f32x4 aRA  = {eb_r, eb_r, eb_r, eb_r},   aRB  = aRA;                     \
            f32x4 aZA  = {eb_z, eb_z, eb_z, eb_z},   aZB  = aZA;                     \
            f32x4 aXNA = {eb_xn, eb_xn, eb_xn, eb_xn}, aXNB = aXNA;                  \
            f32x4 aHNA = {eb_hn, eb_hn, eb_hn, eb_hn}, aHNB = aHNA;                  \
            aRA  = mfma16(axA, we_xr, aRA);   aRB  = mfma16(axB, we_xr, aRB);        \
            aZA  = mfma16(axA, we_xz, aZA);   aZB  = mfma16(axB, we_xz, aZB);        \
            aXNA = mfma16(axA, we_xn, aXNA);  aXNB = mfma16(axB, we_xn, aXNB);       \
            aRA  = mfma16(aA0, we_r[0], aRA);  aRB  = mfma16(aB0, we_r[0], aRB);     \
            aRA  = mfma16(aA1, we_r[1], aRA);  aRB  = mfma16(aB1, we_r[1], aRB);     \
            aRA  = mfma16(aA2, we_r[2], aRA);  aRB  = mfma16(aB2, we_r[2], aRB);     \
            aRA  = mfma16(aA3, we_r[3], aRA);  aRB  = mfma16(aB3, we_r[3], aRB);     \
            aZA  = mfma16(aA0, we_z[0], aZA);  aZB  = mfma16(aB0, we_z[0], aZB);     \
            aZA  = mfma16(aA1, we_z[1], aZA);  aZB  = mfma16(aB1, we_z[1], aZB);     \
            aZA  = mfma16(aA2, we_z[2], aZA);  aZB  = mfma16(aB2, we_z[2], aZB);     \
            aZA  = mfma16(aA3, we_z[3], aZA);  aZB  = mfma16(aB3, we_z[3], aZB);     \
            aHNA = mfma16(aA0, we_hn[0], aHNA); aHNB = mfma16(aB0, we_hn[0], aHNB);  \
            aHNA = mfma16(aA1, we_hn[1], aHNA); aHNB = mfma16(aB1, we_hn[1], aHNB);  \
            aHNA = mfma16(aA2, we_hn[2], aHNA); aHNB = mfma16(aB2, we_hn[2], aHNB);  \
            aHNA = mfma16(aA3, we_hn[3], aHNA); aHNB = mfma16(aB3, we_hn[3], aHNB);  \
            GATES(aRA, aZA, aXNA, aHNA, hoA, OBUF, 0, , , , )                        \
            GATES(aRB, aZB, aXNB, aHNB, hoB, OBUF, 1, , , , )                        \
        } while (0)

        for (int t = 0; t < 64; t += 2) {
            ENC_STEP(0, 1, t + 1);
            ENC_STEP(1, 0, t + 2);
        }
#undef ENC_STEP
    }

    // ================= decoder =================
    float db_r, db_z, db_xn, db_hn;
    { int c = j0 + nl;
      db_r = bias[512 + c]; db_z = bias[640 + c]; db_xn = bias[768 + c]; db_hn = bias[896 + c]; }

    // step 0: xin = 0 -> gx = bih; Whh-only frags, shared across both tiles
    {
        __syncthreads();
        f16x8 aA0 = *(const f16x8*)(&h_s[0][0][nl][c0]);
        f16x8 aA1 = *(const f16x8*)(&h_s[0][0][nl][c1]);
        f16x8 aA2 = *(const f16x8*)(&h_s[0][0][nl][c2]);
        f16x8 aA3 = *(const f16x8*)(&h_s[0][0][nl][c3]);
        f16x8 aB0 = *(const f16x8*)(&h_s[0][1][nl][c0]);
        f16x8 aB1 = *(const f16x8*)(&h_s[0][1][nl][c1]);
        f16x8 aB2 = *(const f16x8*)(&h_s[0][1][nl][c2]);
        f16x8 aB3 = *(const f16x8*)(&h_s[0][1][nl][c3]);
        int gr = j0 + nl;
        f32x4 aRA  = {db_r, db_r, db_r, db_r},   aRB  = aRA;
        f32x4 aZA  = {db_z, db_z, db_z, db_z},   aZB  = aZA;
        f32x4 aHNA = {db_hn, db_hn, db_hn, db_hn}, aHNB = aHNA;
        #pragma unroll
        for (int kt = 0; kt < 4; kt++) {
            f16x8 b0 = *(const f16x8*)(dwhh + gr * 128 + kt * 32 + quad * 8);
            f16x8 b1 = *(const f16x8*)(dwhh + (128 + gr) * 128 + kt * 32 + quad * 8);
            f16x8 b2 = *(const f16x8*)(dwhh + (256 + gr) * 128 + kt * 32 + quad * 8);
            f16x8 aA = (kt == 0) ? aA0 : (kt == 1) ? aA1 : (kt == 2) ? aA2 : aA3;
            f16x8 aB = (kt == 0) ? aB0 : (kt == 1) ? aB1 : (kt == 2) ? aB2 : aB3;
            aRA  = mfma16(aA, b0, aRA);   aRB  = mfma16(aB, b0, aRB);
            aZA  = mfma16(aA, b1, aZA);   aZB  = mfma16(aB, b1, aZB);
            aHNA = mfma16(aA, b2, aHNA);  aHNB = mfma16(aB, b2, aHNB);
        }
        #pragma unroll
        for (int r = 0; r < 4; r++) {
            float ea = fexp2n(aRA[r]), eb = fexp2n(aZA[r]);
            float s1 = 1.0f + ea, s2 = 1.0f + eb;
            float R = __builtin_amdgcn_rcpf(s1 * s2);
            float rg = s2 * R, zg = s1 * R;
            float ec = fexp2n(2.0f * (db_xn + rg * aHNA[r]));
            float ng = (1.0f - ec) * __builtin_amdgcn_rcpf(1.0f + ec);
            float h = ng + zg * (hoA[r] - ng);
            hoA[r] = h;
            h_s[1][0][wrow + r][wcol] = (f16)h;
        }
        #pragma unroll
        for (int r = 0; r < 4; r++) {
            float ea = fexp2n(aRB[r]), eb = fexp2n(aZB[r]);
            float s1 = 1.0f + ea, s2 = 1.0f + eb;
            float R = __builtin_amdgcn_rcpf(s1 * s2);
            float rg = s2 * R, zg = s1 * R;
            float ec = fexp2n(2.0f * (db_xn + rg * aHNB[r]));
            float ng = (1.0f - ec) * __builtin_amdgcn_rcpf(1.0f + ec);
            float h = ng + zg * (hoB[r] - ng);
            hoB[r] = h;
            h_s[1][1][wrow + r][wcol] = (f16)h;
        }
    }
    // steps 1..63: xin == h -> combined weights, shared across both tiles
    {
        f16x8 wd_r[4], wd_z[4], wd_xn[4], wd_hn[4];
        { int gr = j0 + nl;
          #pragma unroll
          for (int kt = 0; kt < 4; kt++) {
              wd_r[kt]  = *(const f16x8*)(dwc + gr * 128 + kt * 32 + quad * 8);
              wd_z[kt]  = *(const f16x8*)(dwc + (128 + gr) * 128 + kt * 32 + quad * 8);
              wd_xn[kt] = *(const f16x8*)(dwc + (256 + gr) * 128 + kt * 32 + quad * 8);
              wd_hn[kt] = *(const f16x8*)(dwc + (384 + gr) * 128 + kt * 32 + quad * 8);
          }
        }

#define DEC_STEP(BUF, OBUF)                                                          \
        do {                                                                         \
            __syncthreads();                                                         \
            f16x8 aA0 = *(const f16x8*)(&h_s[BUF][0][nl][c0]);                       \
            f16x8 aA1 = *(const f16x8*)(&h_s[BUF][0][nl][c1]);                       \
            f16x8 aA2 = *(const f16x8*)(&h_s[BUF][0][nl][c2]);                       \
            f16x8 aA3 = *(const f16x8*)(&h_s[BUF][0][nl][c3]);                       \
            f16x8 aB0 = *(const f16x8*)(&h_s[BUF][1][nl][c0]);                       \
            f16x8 aB1 = *(const f16x8*)(&h_s[BUF][1][nl][c1]);                       \
            f16x8 aB2 = *(const f16x8*)(&h_s[BUF][1][nl][c2]);                       \
            f16x8 aB3 = *(const f16x8*)(&h_s[BUF][1][nl][c3]);                       \
            f32x4 aRA  = {db_r, db_r, db_r, db_r},   aRB  = aRA;                     \
            f32x4 aZA  = {db_z, db_z, db_z, db_z},   aZB  = aZA;                     \
            f32x4 aXNA = {db_xn, db_xn, db_xn, db_xn}, aXNB = aXNA;                  \
            f32x4 aHNA = {db_hn, db_hn, db_hn, db_hn}, aHNB = aHNA;                  \
            aRA  = mfma16(aA0, wd_r[0], aRA);   aRB  = mfma16(aB0, wd_r[0], aRB);    \
            aRA  = mfma16(aA1, wd_r[1], aRA);   aRB  = mfma16(aB1, wd_r[1], aRB);    \
            aRA  = mfma16(aA2, wd_r[2], aRA);   aRB  = mfma16(aB2, wd_r[2], aRB);    \
            aRA  = mfma16(aA3, wd_r[3], aRA);   aRB  = mfma16(aB3, wd_r[3], aRB);    \
            aZA  = mfma16(aA0, wd_z[0], aZA);   aZB  = mfma16(aB0, wd_z[0], aZB);    \
            aZA  = mfma16(aA1, wd_z[1], aZA);   aZB  = mfma16(aB1, wd_z[1], aZB);    \
            aZA  = mfma16(aA2, wd_z[2], aZA);   aZB  = mfma16(aB2, wd_z[2], aZB);    \
            aZA  = mfma16(aA3, wd_z[3], aZA);   aZB  = mfma16(aB3, wd_z[3], aZB);    \
            aXNA = mfma16(aA0, wd_xn[0], aXNA); aXNB = mfma16(aB0, wd_xn[0], aXNB);  \
            aXNA = mfma16(aA1, wd_xn[1], aXNA); aXNB = mfma16(aB1, wd_xn[1], aXNB);  \
            aXNA = mfma16(aA2, wd_xn[2], aXNA); aXNB = mfma16(aB2, wd_xn[2], aXNB);  \
            aXNA = mfma16(aA3, wd_xn[3], aXNA); aXNB = mfma16(aB3, wd_xn[3], aXNB);  \
            aHNA = mfma16(aA0, wd_hn[0], aHNA); aHNB = mfma16(aB0, wd_hn[0], aHNB);  \
            aHNA = mfma16(aA1, wd_hn[1], aHNA); aHNB = mfma16(aB1, wd_hn[1], aHNB);  \
            aHNA = mfma16(aA2, wd_hn[2], aHNA); aHNB = mfma16(aB2, wd_hn[2], aHNB);  \
            aHNA = mfma16(aA3, wd_hn[3], aHNA); aHNB = mfma16(aB3, wd_hn[3], aHNB);  \
            GATES(aRA, aZA, aXNA, aHNA, hoA, OBUF, 0, , , , )                        \
            GATES(aRB, aZB, aXNB, aHNB, hoB, OBUF, 1, , , , )                        \
        } while (0)

        DEC_STEP(1, 0);            // step 1
        for (int t = 2; t < 64; t += 2) {
            DEC_STEP(0, 1);
            DEC_STEP(1, 0);
        }
#undef DEC_STEP
#undef GATES
    }

    // ================= heads (pn_s cols 0..127 already hold z_cnn) =================
    #pragma unroll
    for (int r = 0; r < 4; r++) {
        pn_s[wrow + r][128 + j0 + nl] = hoA[r];
        pn_s[16 + wrow + r][128 + j0 + nl] = hoB[r];
    }
    __syncthreads();

    const int rr = tid & 31, og = tid >> 5;   // og 0..15, rr 0..31
    const float4* pr4 = (const float4*)(&pn_s[rr][0]);
    for (int o = og; o < 79; o += 16) {
        const float* wrow_p = (o < 78) ? (dis_w + o * 256) : value_w;
        float acc = (o < 78) ? dis_b[o] : value_b[0];
        const float4* wr4 = (const float4*)wrow_p;
        #pragma unroll 8
        for (int k = 0; k < 64; k++) {
            float4 a = wr4[k], b = pr4[k];
            acc += a.x * b.x + a.y * b.y + a.z * b.z + a.w * b.w;
        }
        if (o < 78) out[(size_t)(row0 + rr) * 78 + o] = acc;
        else        out[(size_t)8192 * 78 + row0 + rr] = acc;
    }
}

extern "C" void kernel_launch(void* const* d_in, const int* in_sizes, int n_in,
                              void* d_out, int out_size, void* d_ws, size_t ws_size,
                              hipStream_t stream)
{
    (void)in_sizes; (void)n_in; (void)out_size; (void)ws_size;
    const float* cnn  = (const float*)d_in[0];
    const float* lin  = (const float*)d_in[1];
    const float* c1w  = (const float*)d_in[2];
    const float* c1b  = (const float*)d_in[3];
    const float* c2w  = (const float*)d_in[4];
    const float* c2b  = (const float*)d_in[5];
    const float* fcw  = (const float*)d_in[6];
    const float* fcb  = (const float*)d_in[7];
    const float* eWih = (const float*)d_in[8];
    const float* eWhh = (const float*)d_in[9];
    const float* ebih = (const float*)d_in[10];
    const float* ebhh = (const float*)d_in[11];
    const float* dWih = (const float*)d_in[12];
    const float* dWhh = (const float*)d_in[13];
    const float* dbih = (const float*)d_in[14];
    const float* dbhh = (const float*)d_in[15];
    const float* disw = (const float*)d_in[16];
    const float* disb = (const float*)d_in[17];
    const float* vw   = (const float*)d_in[18];
    const float* vb   = (const float*)d_in[19];
    char* ws = (char*)d_ws;
    float* out = (float*)d_out;

    hipLaunchKernelGGL(k_prep, dim3(128), dim3(256), 0, stream,
                       eWih, eWhh, ebih, ebhh, dWih, dWhh, dbih, dbhh,
                       c1w, c2w, fcw, ws);
    hipLaunchKernelGGL(k_gru, dim3(256), dim3(512), 0, stream,
                       cnn, lin, c1b, c2b, fcb, ws, disw, disb, vw, vb, out);
}

// Round 8
// 347.522 us; speedup vs baseline: 1.0017x; 1.0017x over previous
//
#include <hip/hip_runtime.h>

typedef _Float16 f16;
typedef _Float16 f16x8 __attribute__((ext_vector_type(8)));
typedef float f32x4 __attribute__((ext_vector_type(4)));

// ---- workspace layout (bytes) ----
#define WS_ZCNN 0                      // z_cnn f32 [8192][128] (4 MB round-trip)
#define WS_EWIH 4194304                // enc Wih f16 [384][32] (k>=29 zero)
#define WS_EWHH 4218880                // enc Whh f16 [384][128]
#define WS_DWC  4317184                // dec combined f16 [512][128]
#define WS_DWHH 4448256                // dec Whh f16 [384][128]
#define WS_BIAS 4546560                // f32[1024]
#define WS_W1F  4550656                // conv1 B-frags f16 [9][16][32]
#define WS_W2F  4559872                // conv2 B-frags f16 [2][32][32]
#define WS_FCWF 4563968                // fc weights f16 [128][128]

static __device__ __forceinline__ f32x4 mfma16(f16x8 a, f16x8 b, f32x4 c) {
    return __builtin_amdgcn_mfma_f32_16x16x32_f16(a, b, c, 0, 0, 0);
}
static __device__ __forceinline__ float fexp2n(float x) {   // 2^(-x*log2e) = e^-x
    return __builtin_amdgcn_exp2f(x * -1.4426950408889634f);
}

// Cooperative copy of weight rows (128 f16 each) into LDS at 256 B/row with the
// bank XOR swizzle (byte ^= (row&7)<<4). Same XOR on the read side. This gives
// ds_read_b128 the optimal 8-lanes-per-bank-group distribution (unswizzled
// would be 16-way conflicted: 16 nl-lanes share one 16B column slot).
static __device__ __forceinline__ void copy_w_lds(const f16* __restrict__ src,
                                                  char* __restrict__ dst,
                                                  int rows, int tid)
{
    for (int c = tid, e = rows * 16; c < e; c += 512) {
        int row = c >> 4, slot = c & 15;
        *(f16x8*)(dst + row * 256 + ((slot * 16) ^ ((row & 7) << 4))) =
            *(const f16x8*)(src + row * 128 + slot * 8);
    }
}

// ---------------- prep: f32 -> f16 packs (raw values; NO scale folding) ----
__global__ void k_prep(const float* __restrict__ eWih, const float* __restrict__ eWhh,
                       const float* __restrict__ ebih, const float* __restrict__ ebhh,
                       const float* __restrict__ dWih, const float* __restrict__ dWhh,
                       const float* __restrict__ dbih, const float* __restrict__ dbhh,
                       const float* __restrict__ w1, const float* __restrict__ w2,
                       const float* __restrict__ fcw,
                       char* __restrict__ ws)
{
    f16* ewih = (f16*)(ws + WS_EWIH);
    f16* ewhh = (f16*)(ws + WS_EWHH);
    f16* dwc  = (f16*)(ws + WS_DWC);
    f16* dwhh = (f16*)(ws + WS_DWHH);
    float* bias = (float*)(ws + WS_BIAS);
    f16* w1f = (f16*)(ws + WS_W1F);
    f16* w2f = (f16*)(ws + WS_W2F);
    f16* fcwf = (f16*)(ws + WS_FCWF);
    const int total = 12288 + 49152 + 65536 + 49152 + 1024 + 4608 + 2048 + 16384;
    for (int i = blockIdx.x * 256 + threadIdx.x; i < total; i += gridDim.x * 256) {
        int j = i;
        if (j < 12288) { int g = j >> 5, k = j & 31;
            ewih[j] = (f16)((k < 29) ? eWih[g * 29 + k] : 0.0f); continue; }
        j -= 12288;
        if (j < 49152) { ewhh[j] = (f16)eWhh[j]; continue; }
        j -= 49152;
        if (j < 65536) { int row = j >> 7, k = j & 127; float v;
            if (row < 256)      v = dWih[row * 128 + k] + dWhh[row * 128 + k];
            else if (row < 384) v = dWih[row * 128 + k];
            else                v = dWhh[(row - 128) * 128 + k];
            dwc[j] = (f16)v; continue; }
        j -= 65536;
        if (j < 49152) { dwhh[j] = (f16)dWhh[j]; continue; }
        j -= 49152;
        if (j < 1024) {
            if (j < 256)        bias[j] = ebih[j] + ebhh[j];
            else if (j < 384)   bias[j] = ebih[j];
            else if (j < 512)   bias[j] = ebhh[j - 128];
            else if (j < 768)   bias[j] = dbih[j - 512] + dbhh[j - 512];
            else if (j < 896)   bias[j] = dbih[j - 512];
            else                bias[j] = dbhh[j - 640];
            continue; }
        j -= 1024;
        if (j < 4608) {   // w1f[kk][co][k]: w1 (16,27,3,3) OIHW; k>=27 -> 0
            int kk = j >> 9, rem = j & 511, co = rem >> 5, k = rem & 31;
            w1f[j] = (f16)((k < 27) ? w1[co * 243 + k * 9 + kk] : 0.0f); continue; }
        j -= 4608;
        if (j < 2048) {   // w2f[s][co][k]
            int s = j >> 10, rem = j & 1023, co = rem >> 5, k = rem & 31;
            int kk2 = 2 * s + (k >= 16), ci = k & 15;
            w2f[j] = (f16)w2[co * 64 + ci * 4 + kk2]; continue; }
        j -= 2048;
        fcwf[j] = (f16)fcw[j];
    }
}

// -------- fused CNN + GRU + heads: 512 threads, 32 rows/block, grid 256 --------
// R7 structure (passed, absmax 0.015625) with ONE change: recurrence weights
// are staged in a 128 KB dynamic-LDS region (gfx950 allows 160 KB/workgroup)
// instead of being re-streamed from L2 every step. R7 falsified the L2-BW
// theory (halving traffic: null); the remaining stall source is the L2
// latency/bandwidth of the per-step weight stream itself — LDS (120 cyc,
// CU-private) removes it. Weight values are copied bit-exact; all MFMA inputs
// and the gate math are identical to R7 -> output should be bit-identical.
// z_cnn moves to a global f32 round-trip (lossless) to fit the LDS budget;
// the heads reuse the weight-LDS region as pn[32][264].
__global__ __launch_bounds__(512, 2) void k_gru(
    const float* __restrict__ cin,
    const float* __restrict__ lin,
    const float* __restrict__ b1, const float* __restrict__ b2,
    const float* __restrict__ fcb,
    char* __restrict__ ws,
    const float* __restrict__ dis_w, const float* __restrict__ dis_b,
    const float* __restrict__ value_w, const float* __restrict__ value_b,
    float* __restrict__ out)
{
    __shared__ __align__(16) char smem[21504];
    f16 (*h_s)[2][16][136]  = (f16(*)[2][16][136])(smem);          // [buf][tile] 17408 B
    f16 (*x_s)[2][16][32]   = (f16(*)[2][16][32])(smem + 17408);   // [buf][tile] 4096 B
    f16 (*a1f)[9][24]       = (f16(*)[9][24])(smem);               // 6912 B, alias (CNN only)
    f16 (*vf)[136]          = (f16(*)[136])(smem + 8704);          // 4352 B, alias (CNN only)
    extern __shared__ __align__(16) char wlds[];                   // 131072 B dynamic

    const int tid = threadIdx.x;
    const int wv = tid >> 6;
    const int lane = tid & 63;
    const int nl = lane & 15;
    const int quad = lane >> 4;
    const int j0 = wv * 16;
    const int row0 = blockIdx.x * 32;
    const int wswz = (nl & 7) << 4;    // weight-LDS read swizzle (row&7 == nl&7 for all rows used)

// swizzled weight fragment read: f16 row ROW (256B apart), k-slice KT, quad lanes
#define WREAD(ROW, KT) (*(const f16x8*)(wlds + (ROW) * 256 + ((((KT) * 64) + quad * 16) ^ wswz)))

    const f16* ewih = (const f16*)(ws + WS_EWIH);
    const f16* ewhh = (const f16*)(ws + WS_EWHH);
    const f16* dwc  = (const f16*)(ws + WS_DWC);
    const f16* dwhh = (const f16*)(ws + WS_DWHH);
    const float* bias = (const float*)(ws + WS_BIAS);
    const f16* w1f = (const f16*)(ws + WS_W1F);
    const f16* w2f = (const f16*)(ws + WS_W2F);
    const f16* fcwf = (const f16*)(ws + WS_FCWF);
    float* zc = (float*)(ws + WS_ZCNN);

    // issue encoder-weight copy first; its ds_writes complete under the CNN
    copy_w_lds(ewhh, wlds, 384, tid);

    // ============ CNN prologue: 32 images as two groups of 16 ============
    for (int g = 0; g < 2; g++) {
        const float* imgp = cin + (size_t)(row0 + g * 16 + nl) * 1728 + quad * 8;
        float b1v = b1[nl];
        for (int p = wv; p < 9; p += 8) {
            int oy = p / 3, ox = p % 3;
            f32x4 acc = {b1v, b1v, b1v, b1v};
            #pragma unroll
            for (int kk = 0; kk < 9; kk++) {
                f16x8 bw = *(const f16x8*)(w1f + (kk * 16 + nl) * 32 + quad * 8);
                int pix = (2 * oy + kk / 3) * 8 + (2 * ox + kk % 3);
                const float* s = imgp + pix * 27;
                f16x8 a;
                #pragma unroll
                for (int jj = 0; jj < 8; jj++) a[jj] = (f16)s[jj];
                acc = mfma16(a, bw, acc);
            }
            #pragma unroll
            for (int r = 0; r < 4; r++)
                a1f[quad * 4 + r][p][nl] = (f16)fmaxf(acc[r], 0.0f);
        }
        __syncthreads();
        // conv2: 4 positions x 2 nt = 8 units -> one per wave
        {
            int pos = wv >> 1, nt = wv & 1;
            int y = pos >> 1, x = pos & 1;
            float bv = b2[nt * 16 + nl];
            f32x4 acc = {bv, bv, bv, bv};
            #pragma unroll
            for (int s = 0; s < 2; s++) {
                int kk2 = 2 * s + (quad >> 1);
                int pos1 = (y + (kk2 >> 1)) * 3 + (x + (kk2 & 1));
                f16x8 a = *(const f16x8*)(&a1f[nl][pos1][(quad & 1) * 8]);
                f16x8 b = *(const f16x8*)(w2f + ((size_t)s * 32 + nt * 16 + nl) * 32 + quad * 8);
                acc = mfma16(a, b, acc);
            }
            #pragma unroll
            for (int r = 0; r < 4; r++)
                vf[quad * 4 + r][(nt * 16 + nl) * 4 + (y * 2 + x)] = (f16)fmaxf(acc[r], 0.0f);
        }
        __syncthreads();
        // fc 128->128: wave wv -> outputs wv*16..wv*16+15, z_cnn to global ws
        {
            int o = wv * 16 + nl;
            float bv = fcb[o];
            f32x4 acc = {bv, bv, bv, bv};
            #pragma unroll
            for (int kt = 0; kt < 4; kt++) {
                f16x8 a = *(const f16x8*)(&vf[nl][kt * 32 + quad * 8]);
                f16x8 b = *(const f16x8*)(fcwf + o * 128 + kt * 32 + quad * 8);
                acc = mfma16(a, b, acc);
            }
            #pragma unroll
            for (int r = 0; r < 4; r++)
                zc[(size_t)(row0 + g * 16 + quad * 4 + r) * 128 + o] = fmaxf(acc[r], 0.0f);
        }
        __syncthreads();   // a1f/vf dead; also covers enc-weight copy completion
    }

    for (int i = tid; i < 2 * 2 * 16 * 136; i += 512) ((f16*)h_s)[i] = (f16)0.0f;

    const int rsw = (nl & 8) ? 16 : 0;    // read-side swizzle (row = nl)
    const int wrow = quad * 4;            // write rows wrow..wrow+3
    const int wsw = (quad >= 2) ? 16 : 0; // write-side swizzle (rows 8-15)
    const int wcol = (j0 + nl + wsw) & 127;
    const int c0 = (quad * 8 + rsw) & 127;
    const int c1 = (32 + quad * 8 + rsw) & 127;
    const int c2 = (64 + quad * 8 + rsw) & 127;
    const int c3 = (96 + quad * 8 + rsw) & 127;

    float hoA[4], hoB[4];
    #pragma unroll
    for (int r = 0; r < 4; r++) { hoA[r] = 0.0f; hoB[r] = 0.0f; }

    const int xr = tid >> 5, xc = tid & 31;   // x staging: 16 rows x 32 cols per tile
    const bool xok = (xc < 29);
    const size_t lin_baseA = (size_t)(row0 + xr) * 1856 + xc;
    const size_t lin_baseB = (size_t)(row0 + 16 + xr) * 1856 + xc;

#define GATES(AR, AZ, AXN, AHN, HO, OB, TI)                                          \
        _Pragma("unroll")                                                            \
        for (int r = 0; r < 4; r++) {                                                \
            float ea = fexp2n((AR)[r]), eb = fexp2n((AZ)[r]);                        \
            float s1 = 1.0f + ea, s2 = 1.0f + eb;                                    \
            float R = __builtin_amdgcn_rcpf(s1 * s2);                                \
            float rg = s2 * R, zg = s1 * R;                                          \
            float ec = fexp2n(2.0f * ((AXN)[r] + rg * (AHN)[r]));                    \
            float ng = (1.0f - ec) * __builtin_amdgcn_rcpf(1.0f + ec);               \
            float h = ng + zg * ((HO)[r] - ng);                                      \
            (HO)[r] = h;                                                             \
            h_s[OB][TI][wrow + r][wcol] = (f16)h;                                    \
        }

    // ================= encoder =================
    {
        float eb_r, eb_z, eb_xn, eb_hn;
        { int c = j0 + nl;
          eb_r = bias[c]; eb_z = bias[128 + c]; eb_xn = bias[256 + c]; eb_hn = bias[384 + c]; }
        f16x8 we_r[4], we_z[4], we_hn[4], we_xr, we_xz, we_xn;
        { int gr = j0 + nl;
          #pragma unroll
          for (int kt = 0; kt < 4; kt++) {
              we_r[kt]  = WREAD(gr, kt);
              we_z[kt]  = WREAD(128 + gr, kt);
              we_hn[kt] = WREAD(256 + gr, kt);
          }
          we_xr = *(const f16x8*)(ewih + gr * 32 + quad * 8);
          we_xz = *(const f16x8*)(ewih + (128 + gr) * 32 + quad * 8);
          we_xn = *(const f16x8*)(ewih + (256 + gr) * 32 + quad * 8);
        }

        float xvA = xok ? lin[lin_baseA] : 0.0f;
        float xvB = xok ? lin[lin_baseB] : 0.0f;

#define ENC_STEP(BUF, OBUF, TN)                                                      \
        do {                                                                         \
            x_s[BUF][0][xr][xc] = (f16)xvA;                                          \
            x_s[BUF][1][xr][xc] = (f16)xvB;                                          \
            __syncthreads();                                                         \
            f16x8 axA = *(const f16x8*)(&x_s[BUF][0][nl][quad * 8]);                 \
            f16x8 axB = *(const f16x8*)(&x_s[BUF][1][nl][quad * 8]);                 \
            f16x8 aA0 = *(const f16x8*)(&h_s[BUF][0][nl][c0]);                       \
            f16x8 aA1 = *(const f16x8*)(&h_s[BUF][0][nl][c1]);                       \
            f16x8 aA2 = *(const f16x8*)(&h_s[BUF][0][nl][c2]);                       \
            f16x8 aA3 = *(const f16x8*)(&h_s[BUF][0][nl][c3]);                       \
            f16x8 aB0 = *(const f16x8*)(&h_s[BUF][1][nl][c0]);                       \
            f16x8 aB1 = *(const f16x8*)(&h_s[BUF][1][nl][c1]);                       \
            f16x8 aB2 = *(const f16x8*)(&h_s[BUF][1][nl][c2]);                       \
            f16x8 aB3 = *(const f16x8*)(&h_s[BUF][1][nl][c3]);                       \
            if ((TN) < 64) {                                                         \
                xvA = xok ? lin[lin_baseA + (TN) * 29] : 0.0f;                       \
                xvB = xok ? lin[lin_baseB + (TN) * 29] : 0.0f;                       \
            }                                                                        \
            f32x4 aRA  = {eb_r, eb_r, eb_r, eb_r},   aRB  = aRA;                     \
            f32x4 aZA  = {eb_z, eb_z, eb_z, eb_z},   aZB  = aZA;                     \
            f32x4 aXNA = {eb_xn, eb_xn, eb_xn, eb_xn}, aXNB = aXNA;                  \
            f32x4 aHNA = {eb_hn, eb_hn, eb_hn, eb_hn}, aHNB = aHNA;                  \
            aRA  = mfma16(axA, we_xr, aRA);   aRB  = mfma16(axB, we_xr, aRB);        \
            aZA  = mfma16(axA, we_xz, aZA);   aZB  = mfma16(axB, we_xz, aZB);        \
            aXNA = mfma16(axA, we_xn, aXNA);  aXNB = mfma16(axB, we_xn, aXNB);       \
            aRA  = mfma16(aA0, we_r[0], aRA);  aRB  = mfma16(aB0, we_r[0], aRB);     \
            aRA  = mfma16(aA1, we_r[1], aRA);  aRB  = mfma16(aB1, we_r[1], aRB);     \
            aRA  = mfma16(aA2, we_r[2], aRA);  aRB  = mfma16(aB2, we_r[2], aRB);     \
            aRA  = mfma16(aA3, we_r[3], aRA);  aRB  = mfma16(aB3, we_r[3], aRB);     \
            aZA  = mfma16(aA0, we_z[0], aZA);  aZB  = mfma16(aB0, we_z[0], aZB);     \
            aZA  = mfma16(aA1, we_z[1], aZA);  aZB  = mfma16(aB1, we_z[1], aZB);     \
            aZA  = mfma16(aA2, we_z[2], aZA);  aZB  = mfma16(aB2, we_z[2], aZB);     \
            aZA  = mfma16(aA3, we_z[3], aZA);  aZB  = mfma16(aB3, we_z[3], aZB);     \
            aHNA = mfma16(aA0, we_hn[0], aHNA); aHNB = mfma16(aB0, we_hn[0], aHNB);  \
            aHNA = mfma16(aA1, we_hn[1], aHNA); aHNB = mfma16(aB1, we_hn[1], aHNB);  \
            aHNA = mfma16(aA2, we_hn[2], aHNA); aHNB = mfma16(aB2, we_hn[2], aHNB);  \
            aHNA = mfma16(aA3, we_hn[3], aHNA); aHNB = mfma16(aB3, we_hn[3], aHNB);  \
            GATES(aRA, aZA, aXNA, aHNA, hoA, OBUF, 0)                                \
            GATES(aRB, aZB, aXNB, aHNB, hoB, OBUF, 1)                                \
        } while (0)

        for (int t = 0; t < 64; t += 2) {
            ENC_STEP(0, 1, t + 1);
            ENC_STEP(1, 0, t + 2);
        }
#undef ENC_STEP
    }

    // ================= decoder =================
    float db_r, db_z, db_xn, db_hn;
    { int c = j0 + nl;
      db_r = bias[512 + c]; db_z = bias[640 + c]; db_xn = bias[768 + c]; db_hn = bias[896 + c]; }

    __syncthreads();                    // all encoder wlds reads complete
    copy_w_lds(dwc, wlds, 512, tid);    // overwrite with decoder weights; overlaps step 0

    // step 0: xin = 0 -> gx = bih; Whh-only frags streamed from GLOBAL (once)
    {
        f16x8 aA0 = *(const f16x8*)(&h_s[0][0][nl][c0]);
        f16x8 aA1 = *(const f16x8*)(&h_s[0][0][nl][c1]);
        f16x8 aA2 = *(const f16x8*)(&h_s[0][0][nl][c2]);
        f16x8 aA3 = *(const f16x8*)(&h_s[0][0][nl][c3]);
        f16x8 aB0 = *(const f16x8*)(&h_s[0][1][nl][c0]);
        f16x8 aB1 = *(const f16x8*)(&h_s[0][1][nl][c1]);
        f16x8 aB2 = *(const f16x8*)(&h_s[0][1][nl][c2]);
        f16x8 aB3 = *(const f16x8*)(&h_s[0][1][nl][c3]);
        int gr = j0 + nl;
        f32x4 aRA  = {db_r, db_r, db_r, db_r},   aRB  = aRA;
        f32x4 aZA  = {db_z, db_z, db_z, db_z},   aZB  = aZA;
        f32x4 aHNA = {db_hn, db_hn, db_hn, db_hn}, aHNB = aHNA;
        #pragma unroll
        for (int kt = 0; kt < 4; kt++) {
            f16x8 b0 = *(const f16x8*)(dwhh + gr * 128 + kt * 32 + quad * 8);
            f16x8 b1 = *(const f16x8*)(dwhh + (128 + gr) * 128 + kt * 32 + quad * 8);
            f16x8 b2 = *(const f16x8*)(dwhh + (256 + gr) * 128 + kt * 32 + quad * 8);
            f16x8 aA = (kt == 0) ? aA0 : (kt == 1) ? aA1 : (kt == 2) ? aA2 : aA3;
            f16x8 aB = (kt == 0) ? aB0 : (kt == 1) ? aB1 : (kt == 2) ? aB2 : aB3;
            aRA  = mfma16(aA, b0, aRA);   aRB  = mfma16(aB, b0, aRB);
            aZA  = mfma16(aA, b1, aZA);   aZB  = mfma16(aB, b1, aZB);
            aHNA = mfma16(aA, b2, aHNA);  aHNB = mfma16(aB, b2, aHNB);
        }
        #pragma unroll
        for (int r = 0; r < 4; r++) {
            float ea = fexp2n(aRA[r]), eb = fexp2n(aZA[r]);
            float s1 = 1.0f + ea, s2 = 1.0f + eb;
            float R = __builtin_amdgcn_rcpf(s1 * s2);
            float rg = s2 * R, zg = s1 * R;
            float ec = fexp2n(2.0f * (db_xn + rg * aHNA[r]));
            float ng = (1.0f - ec) * __builtin_amdgcn_rcpf(1.0f + ec);
            float h = ng + zg * (hoA[r] - ng);
            hoA[r] = h;
            h_s[1][0][wrow + r][wcol] = (f16)h;
        }
        #pragma unroll
        for (int r = 0; r < 4; r++) {
            float ea = fexp2n(aRB[r]), eb = fexp2n(aZB[r]);
            float s1 = 1.0f + ea, s2 = 1.0f + eb;
            float R = __builtin_amdgcn_rcpf(s1 * s2);
            float rg = s2 * R, zg = s1 * R;
            float ec = fexp2n(2.0f * (db_xn + rg * aHNB[r]));
            float ng = (1.0f - ec) * __builtin_amdgcn_rcpf(1.0f + ec);
            float h = ng + zg * (hoB[r] - ng);
            hoB[r] = h;
            h_s[1][1][wrow + r][wcol] = (f16)h;
        }
    }
    // steps 1..63: xin == h -> combined weights from LDS
    {
        f16x8 wd_r[4], wd_z[4], wd_xn[4], wd_hn[4];
        { int gr = j0 + nl;
          #pragma unroll
          for (int kt = 0; kt < 4; kt++) {
              wd_r[kt]  = WREAD(gr, kt);
              wd_z[kt]  = WREAD(128 + gr, kt);
              wd_xn[kt] = WREAD(256 + gr, kt);
              wd_hn[kt] = WREAD(384 + gr, kt);
          }
        }

#define DEC_STEP(BUF, OBUF)                                                          \
        do {                                                                         \
            __syncthreads();                                                         \
            f16x8 aA0 = *(const f16x8*)(&h_s[BUF][0][nl][c0]);                       \
            f16x8 aA1 = *(const f16x8*)(&h_s[BUF][0][nl][c1]);                       \
            f16x8 aA2 = *(const f16x8*)(&h_s[BUF][0][nl][c2]);                       \
            f16x8 aA3 = *(const f16x8*)(&h_s[BUF][0][nl][c3]);                       \
            f16x8 aB0 = *(const f16x8*)(&h_s[BUF][1][nl][c0]);                       \
            f16x8 aB1 = *(const f16x8*)(&h_s[BUF][1][nl][c1]);                       \
            f16x8 aB2 = *(const f16x8*)(&h_s[BUF][1][nl][c2]);                       \
            f16x8 aB3 = *(const f16x8*)(&h_s[BUF][1][nl][c3]);                       \
            f32x4 aRA  = {db_r, db_r, db_r, db_r},   aRB  = aRA;                     \
            f32x4 aZA  = {db_z, db_z, db_z, db_z},   aZB  = aZA;                     \
            f32x4 aXNA = {db_xn, db_xn, db_xn, db_xn}, aXNB = aXNA;                  \
            f32x4 aHNA = {db_hn, db_hn, db_hn, db_hn}, aHNB = aHNA;                  \
            aRA  = mfma16(aA0, wd_r[0], aRA);   aRB  = mfma16(aB0, wd_r[0], aRB);    \
            aRA  = mfma16(aA1, wd_r[1], aRA);   aRB  = mfma16(aB1, wd_r[1], aRB);    \
            aRA  = mfma16(aA2, wd_r[2], aRA);   aRB  = mfma16(aB2, wd_r[2], aRB);    \
            aRA  = mfma16(aA3, wd_r[3], aRA);   aRB  = mfma16(aB3, wd_r[3], aRB);    \
            aZA  = mfma16(aA0, wd_z[0], aZA);   aZB  = mfma16(aB0, wd_z[0], aZB);    \
            aZA  = mfma16(aA1, wd_z[1], aZA);   aZB  = mfma16(aB1, wd_z[1], aZB);    \
            aZA  = mfma16(aA2, wd_z[2], aZA);   aZB  = mfma16(aB2, wd_z[2], aZB);    \
            aZA  = mfma16(aA3, wd_z[3], aZA);   aZB  = mfma16(aB3, wd_z[3], aZB);    \
            aXNA = mfma16(aA0, wd_xn[0], aXNA); aXNB = mfma16(aB0, wd_xn[0], aXNB);  \
            aXNA = mfma16(aA1, wd_xn[1], aXNA); aXNB = mfma16(aB1, wd_xn[1], aXNB);  \
            aXNA = mfma16(aA2, wd_xn[2], aXNA); aXNB = mfma16(aB2, wd_xn[2], aXNB);  \
            aXNA = mfma16(aA3, wd_xn[3], aXNA); aXNB = mfma16(aB3, wd_xn[3], aXNB);  \
            aHNA = mfma16(aA0, wd_hn[0], aHNA); aHNB = mfma16(aB0, wd_hn[0], aHNB);  \
            aHNA = mfma16(aA1, wd_hn[1], aHNA); aHNB = mfma16(aB1, wd_hn[1], aHNB);  \
            aHNA = mfma16(aA2, wd_hn[2], aHNA); aHNB = mfma16(aB2, wd_hn[2], aHNB);  \
            aHNA = mfma16(aA3, wd_hn[3], aHNA); aHNB = mfma16(aB3, wd_hn[3], aHNB);  \
            GATES(aRA, aZA, aXNA, aHNA, hoA, OBUF, 0)                                \
            GATES(aRB, aZB, aXNB, aHNB, hoB, OBUF, 1)                                \
        } while (0)

        DEC_STEP(1, 0);            // step 1 (barrier covers dwc copy + h_s[1])
        for (int t = 2; t < 64; t += 2) {
            DEC_STEP(0, 1);
            DEC_STEP(1, 0);
        }
#undef DEC_STEP
#undef GATES
    }

    // ================= heads: reuse wlds as pn[32][264] =================
    __syncthreads();                    // all dwc LDS reads complete before overwrite
    float (*pn)[264] = (float(*)[264])wlds;
    for (int i = tid; i < 32 * 32; i += 512) {          // z_cnn reload: 32 rows x 32 float4
        int row = i >> 5, c4 = i & 31;
        *(float4*)(&pn[row][c4 * 4]) =
            *(const float4*)(zc + (size_t)(row0 + row) * 128 + c4 * 4);
    }
    #pragma unroll
    for (int r = 0; r < 4; r++) {
        pn[wrow + r][128 + j0 + nl] = hoA[r];
        pn[16 + wrow + r][128 + j0 + nl] = hoB[r];
    }
    __syncthreads();

    const int rr = tid & 31, og = tid >> 5;   // og 0..15, rr 0..31
    const float4* pr4 = (const float4*)(&pn[rr][0]);
    for (int o = og; o < 79; o += 16) {
        const float* wrow_p = (o < 78) ? (dis_w + o * 256) : value_w;
        float acc = (o < 78) ? dis_b[o] : value_b[0];
        const float4* wr4 = (const float4*)wrow_p;
        #pragma unroll 8
        for (int k = 0; k < 64; k++) {
            float4 a = wr4[k], b = pr4[k];
            acc += a.x * b.x + a.y * b.y + a.z * b.z + a.w * b.w;
        }
        if (o < 78) out[(size_t)(row0 + rr) * 78 + o] = acc;
        else        out[(size_t)8192 * 78 + row0 + rr] = acc;
    }
#undef WREAD
}

extern "C" void kernel_launch(void* const* d_in, const int* in_sizes, int n_in,
                              void* d_out, int out_size, void* d_ws, size_t ws_size,
                              hipStream_t stream)
{
    (void)in_sizes; (void)n_in; (void)out_size; (void)ws_size;
    const float* cnn  = (const float*)d_in[0];
    const float* lin  = (const float*)d_in[1];
    const float* c1w  = (const float*)d_in[2];
    const float* c1b  = (const float*)d_in[3];
    const float* c2w  = (const float*)d_in[4];
    const float* c2b  = (const float*)d_in[5];
    const float* fcw  = (const float*)d_in[6];
    const float* fcb  = (const float*)d_in[7];
    const float* eWih = (const float*)d_in[8];
    const float* eWhh = (const float*)d_in[9];
    const float* ebih = (const float*)d_in[10];
    const float* ebhh = (const float*)d_in[11];
    const float* dWih = (const float*)d_in[12];
    const float* dWhh = (const float*)d_in[13];
    const float* dbih = (const float*)d_in[14];
    const float* dbhh = (const float*)d_in[15];
    const float* disw = (const float*)d_in[16];
    const float* disb = (const float*)d_in[17];
    const float* vw   = (const float*)d_in[18];
    const float* vb   = (const float*)d_in[19];
    char* ws = (char*)d_ws;
    float* out = (float*)d_out;

    hipLaunchKernelGGL(k_prep, dim3(128), dim3(256), 0, stream,
                       eWih, eWhh, ebih, ebhh, dWih, dWhh, dbih, dbhh,
                       c1w, c2w, fcw, ws);
    hipLaunchKernelGGL(k_gru, dim3(256), dim3(512), 131072, stream,
                       cnn, lin, c1b, c2b, fcb, ws, disw, disb, vw, vb, out);
}

// Round 9
// 330.291 us; speedup vs baseline: 1.0539x; 1.0522x over previous
//
#include <hip/hip_runtime.h>

typedef _Float16 f16;
typedef _Float16 f16x8 __attribute__((ext_vector_type(8)));
typedef float f32x4 __attribute__((ext_vector_type(4)));

// ---- workspace layout (bytes) ----
#define WS_EWIH 4194304                // enc Wih f16 [384][32] (k>=29 zero)
#define WS_EWHH 4218880                // enc Whh f16 [384][128]
#define WS_DWC  4317184                // dec combined f16 [512][128]
#define WS_DWHH 4448256                // dec Whh f16 [384][128]
#define WS_BIAS 4546560                // f32[1024]
#define WS_W1F  4550656                // conv1 B-frags f16 [9][16][32]
#define WS_W2F  4559872                // conv2 B-frags f16 [2][32][32]
#define WS_FCWF 4563968                // fc weights f16 [128][128]

static __device__ __forceinline__ f32x4 mfma16(f16x8 a, f16x8 b, f32x4 c) {
    return __builtin_amdgcn_mfma_f32_16x16x32_f16(a, b, c, 0, 0, 0);
}
static __device__ __forceinline__ float fexp2n(float x) {   // 2^(-x*log2e) = e^-x
    return __builtin_amdgcn_exp2f(x * -1.4426950408889634f);
}

// ---------------- prep: f32 -> f16 packs (raw values; NO scale folding) ----
__global__ void k_prep(const float* __restrict__ eWih, const float* __restrict__ eWhh,
                       const float* __restrict__ ebih, const float* __restrict__ ebhh,
                       const float* __restrict__ dWih, const float* __restrict__ dWhh,
                       const float* __restrict__ dbih, const float* __restrict__ dbhh,
                       const float* __restrict__ w1, const float* __restrict__ w2,
                       const float* __restrict__ fcw,
                       char* __restrict__ ws)
{
    f16* ewih = (f16*)(ws + WS_EWIH);
    f16* ewhh = (f16*)(ws + WS_EWHH);
    f16* dwc  = (f16*)(ws + WS_DWC);
    f16* dwhh = (f16*)(ws + WS_DWHH);
    float* bias = (float*)(ws + WS_BIAS);
    f16* w1f = (f16*)(ws + WS_W1F);
    f16* w2f = (f16*)(ws + WS_W2F);
    f16* fcwf = (f16*)(ws + WS_FCWF);
    const int total = 12288 + 49152 + 65536 + 49152 + 1024 + 4608 + 2048 + 16384;
    for (int i = blockIdx.x * 256 + threadIdx.x; i < total; i += gridDim.x * 256) {
        int j = i;
        if (j < 12288) { int g = j >> 5, k = j & 31;
            ewih[j] = (f16)((k < 29) ? eWih[g * 29 + k] : 0.0f); continue; }
        j -= 12288;
        if (j < 49152) { ewhh[j] = (f16)eWhh[j]; continue; }
        j -= 49152;
        if (j < 65536) { int row = j >> 7, k = j & 127; float v;
            if (row < 256)      v = dWih[row * 128 + k] + dWhh[row * 128 + k];
            else if (row < 384) v = dWih[row * 128 + k];
            else                v = dWhh[(row - 128) * 128 + k];
            dwc[j] = (f16)v; continue; }
        j -= 65536;
        if (j < 49152) { dwhh[j] = (f16)dWhh[j]; continue; }
        j -= 49152;
        if (j < 1024) {
            if (j < 256)        bias[j] = ebih[j] + ebhh[j];
            else if (j < 384)   bias[j] = ebih[j];
            else if (j < 512)   bias[j] = ebhh[j - 128];
            else if (j < 768)   bias[j] = dbih[j - 512] + dbhh[j - 512];
            else if (j < 896)   bias[j] = dbih[j - 512];
            else                bias[j] = dbhh[j - 640];
            continue; }
        j -= 1024;
        if (j < 4608) {   // w1f[kk][co][k]: w1 (16,27,3,3) OIHW; k>=27 -> 0
            int kk = j >> 9, rem = j & 511, co = rem >> 5, k = rem & 31;
            w1f[j] = (f16)((k < 27) ? w1[co * 243 + k * 9 + kk] : 0.0f); continue; }
        j -= 4608;
        if (j < 2048) {   // w2f[s][co][k]
            int s = j >> 10, rem = j & 1023, co = rem >> 5, k = rem & 31;
            int kk2 = 2 * s + (k >= 16), ci = k & 15;
            w2f[j] = (f16)w2[co * 64 + ci * 4 + kk2]; continue; }
        j -= 2048;
        fcwf[j] = (f16)fcw[j];
    }
}

// ---------------- fused CNN + GRU + heads: 512 threads, 16 rows/block ----------------
// BASELINE structure (best: 224 us; 16 waves/CU, 2 blocks/CU naturally stagger
// phases). R7/R8 proved the weight path (L2 vs LDS) is irrelevant — the kernel
// is issue-bound on VALU+MFMA (~75-80% combined pipe busy). This round cuts
// the VALU term: gate math rewritten as f32x4 vector arithmetic so the backend
// can select CDNA's full-rate packed-f32 ops (v_pk_mul/add/fma_f32), halving
// the mul/add/fma instruction count. Packed ops are two independent IEEE f32
// ops -> bit-identical; the (2*t)*(-log2e) -> t*(-2*log2e) fold is exact.
__global__ __launch_bounds__(512, 4) void k_gru(
    const float* __restrict__ cin,
    const float* __restrict__ lin,
    const float* __restrict__ b1, const float* __restrict__ b2,
    const float* __restrict__ fcb,
    const char* __restrict__ ws,
    const float* __restrict__ dis_w, const float* __restrict__ dis_b,
    const float* __restrict__ value_w, const float* __restrict__ value_b,
    float* __restrict__ out)
{
    __shared__ __align__(16) char smem[32000];
    f16 (*h_s)[16][136]  = (f16(*)[16][136])(smem);            // 8704 B
    f16 (*x_s)[16][32]   = (f16(*)[16][32])(smem + 8704);      // 2048 B
    float (*pn_s)[264]   = (float(*)[264])(smem + 10752);      // 16896 B
    f16 (*a1f)[9][24]    = (f16(*)[9][24])(smem);              // 6912 B, aliases h_s (CNN phase only)
    f16 (*vf)[136]       = (f16(*)[136])(smem + 27648);        // 4352 B

    const int tid = threadIdx.x;
    const int wv = tid >> 6;
    const int lane = tid & 63;
    const int nl = lane & 15;
    const int quad = lane >> 4;
    const int j0 = wv * 16;
    const int row0 = blockIdx.x * 16;

    const f16* ewih = (const f16*)(ws + WS_EWIH);
    const f16* ewhh = (const f16*)(ws + WS_EWHH);
    const f16* dwc  = (const f16*)(ws + WS_DWC);
    const f16* dwhh = (const f16*)(ws + WS_DWHH);
    const float* bias = (const float*)(ws + WS_BIAS);
    const f16* w1f = (const f16*)(ws + WS_W1F);
    const f16* w2f = (const f16*)(ws + WS_W2F);
    const f16* fcwf = (const f16*)(ws + WS_FCWF);

    // ================= CNN prologue (16 images = this block's rows) =================
    {
        const float* imgp = cin + (size_t)(row0 + nl) * 1728 + quad * 8;
        float b1v = b1[nl];
        for (int p = wv; p < 9; p += 8) {
            int oy = p / 3, ox = p % 3;
            f32x4 acc = {b1v, b1v, b1v, b1v};
            #pragma unroll
            for (int kk = 0; kk < 9; kk++) {
                f16x8 bw = *(const f16x8*)(w1f + (kk * 16 + nl) * 32 + quad * 8);
                int pix = (2 * oy + kk / 3) * 8 + (2 * ox + kk % 3);
                const float* s = imgp + pix * 27;
                f16x8 a;
                #pragma unroll
                for (int jj = 0; jj < 8; jj++) a[jj] = (f16)s[jj];
                acc = mfma16(a, bw, acc);
            }
            #pragma unroll
            for (int r = 0; r < 4; r++)
                a1f[quad * 4 + r][p][nl] = (f16)fmaxf(acc[r], 0.0f);
        }
        __syncthreads();
        // conv2: 4 positions x 2 nt = 8 units -> one per wave
        {
            int pos = wv >> 1, nt = wv & 1;
            int y = pos >> 1, x = pos & 1;
            float bv = b2[nt * 16 + nl];
            f32x4 acc = {bv, bv, bv, bv};
            #pragma unroll
            for (int s = 0; s < 2; s++) {
                int kk2 = 2 * s + (quad >> 1);
                int pos1 = (y + (kk2 >> 1)) * 3 + (x + (kk2 & 1));
                f16x8 a = *(const f16x8*)(&a1f[nl][pos1][(quad & 1) * 8]);
                f16x8 b = *(const f16x8*)(w2f + ((size_t)s * 32 + nt * 16 + nl) * 32 + quad * 8);
                acc = mfma16(a, b, acc);
            }
            #pragma unroll
            for (int r = 0; r < 4; r++)
                vf[quad * 4 + r][(nt * 16 + nl) * 4 + (y * 2 + x)] = (f16)fmaxf(acc[r], 0.0f);
        }
        __syncthreads();
        // fc 128->128: wave wv -> outputs wv*16..wv*16+15, straight into pn_s[:, 0..127]
        {
            int o = wv * 16 + nl;
            float bv = fcb[o];
            f32x4 acc = {bv, bv, bv, bv};
            #pragma unroll
            for (int kt = 0; kt < 4; kt++) {
                f16x8 a = *(const f16x8*)(&vf[nl][kt * 32 + quad * 8]);
                f16x8 b = *(const f16x8*)(fcwf + o * 128 + kt * 32 + quad * 8);
                acc = mfma16(a, b, acc);
            }
            #pragma unroll
            for (int r = 0; r < 4; r++)
                pn_s[quad * 4 + r][o] = fmaxf(acc[r], 0.0f);
        }
        __syncthreads();   // a1f dead; safe to zero h_s below
    }

    for (int i = tid; i < 2 * 16 * 136; i += 512) ((f16*)h_s)[i] = (f16)0.0f;

    const int rsw = (nl & 8) ? 16 : 0;    // read-side swizzle (row = nl)
    const int wrow = quad * 4;            // write rows wrow..wrow+3
    const int wsw = (quad >= 2) ? 16 : 0; // write-side swizzle (rows 8-15)
    const int wcol = (j0 + nl + wsw) & 127;
    const int c0 = (quad * 8 + rsw) & 127;
    const int c1 = (32 + quad * 8 + rsw) & 127;
    const int c2 = (64 + quad * 8 + rsw) & 127;
    const int c3 = (96 + quad * 8 + rsw) & 127;

    f32x4 ho = {0.0f, 0.0f, 0.0f, 0.0f};

    const int xr = tid >> 5, xc = tid & 31;   // x staging: 16 rows x 32 cols
    const bool xok = (xc < 29);
    const size_t lin_base = (size_t)(row0 + xr) * 1856 + xc;

// Vectorized gate math on f32x4 (targets v_pk_* packed f32).
// Scalar lanes only for exp2/rcp (transcendental, no packed form).
// Bit-identical to the scalar baseline: packed ops are elementwise IEEE;
// t*(-2*log2e) == (2*t)*(-log2e) exactly (x2 is an exponent bump).
#define GATESV(OB)                                                                   \
        do {                                                                         \
            const f32x4 onev = {1.0f, 1.0f, 1.0f, 1.0f};                             \
            f32x4 mR = aR * -1.4426950408889634f;                                    \
            f32x4 mZ = aZ * -1.4426950408889634f;                                    \
            f32x4 ea, eb;                                                            \
            _Pragma("unroll")                                                        \
            for (int r = 0; r < 4; r++) {                                            \
                ea[r] = __builtin_amdgcn_exp2f(mR[r]);                               \
                eb[r] = __builtin_amdgcn_exp2f(mZ[r]);                               \
            }                                                                        \
            f32x4 s1 = onev + ea, s2 = onev + eb;                                    \
            f32x4 pp = s1 * s2, Rv;                                                  \
            _Pragma("unroll")                                                        \
            for (int r = 0; r < 4; r++) Rv[r] = __builtin_amdgcn_rcpf(pp[r]);        \
            f32x4 rg = s2 * Rv, zg = s1 * Rv;                                        \
            f32x4 tv = (aXN + rg * aHN) * -2.8853900817779268f;                      \
            f32x4 ec;                                                                \
            _Pragma("unroll")                                                        \
            for (int r = 0; r < 4; r++) ec[r] = __builtin_amdgcn_exp2f(tv[r]);       \
            f32x4 num = onev - ec, den = onev + ec, Rd;                              \
            _Pragma("unroll")                                                        \
            for (int r = 0; r < 4; r++) Rd[r] = __builtin_amdgcn_rcpf(den[r]);       \
            f32x4 ng = num * Rd;                                                     \
            ho = ng + zg * (ho - ng);                                                \
            _Pragma("unroll")                                                        \
            for (int r = 0; r < 4; r++)                                              \
                h_s[OB][wrow + r][wcol] = (f16)ho[r];                                \
        } while (0)

    // ================= encoder =================
    {
        float eb_r, eb_z, eb_xn, eb_hn;
        { int c = j0 + nl;
          eb_r = bias[c]; eb_z = bias[128 + c]; eb_xn = bias[256 + c]; eb_hn = bias[384 + c]; }
        f16x8 we_r[4], we_z[4], we_hn[4], we_xr, we_xz, we_xn;
        { int gr = j0 + nl;
          #pragma unroll
          for (int kt = 0; kt < 4; kt++) {
              we_r[kt]  = *(const f16x8*)(ewhh + gr * 128 + kt * 32 + quad * 8);
              we_z[kt]  = *(const f16x8*)(ewhh + (128 + gr) * 128 + kt * 32 + quad * 8);
              we_hn[kt] = *(const f16x8*)(ewhh + (256 + gr) * 128 + kt * 32 + quad * 8);
          }
          we_xr = *(const f16x8*)(ewih + gr * 32 + quad * 8);
          we_xz = *(const f16x8*)(ewih + (128 + gr) * 32 + quad * 8);
          we_xn = *(const f16x8*)(ewih + (256 + gr) * 32 + quad * 8);
        }

        float xv = xok ? lin[lin_base] : 0.0f;

#define ENC_STEP(BUF, OBUF, TN)                                                      \
        do {                                                                         \
            x_s[BUF][xr][xc] = (f16)xv;                                              \
            __syncthreads();                                                         \
            f16x8 ax = *(const f16x8*)(&x_s[BUF][nl][quad * 8]);                     \
            f16x8 ah0 = *(const f16x8*)(&h_s[BUF][nl][c0]);                          \
            f16x8 ah1 = *(const f16x8*)(&h_s[BUF][nl][c1]);                          \
            f16x8 ah2 = *(const f16x8*)(&h_s[BUF][nl][c2]);                          \
            f16x8 ah3 = *(const f16x8*)(&h_s[BUF][nl][c3]);                          \
            if ((TN) < 64) xv = xok ? lin[lin_base + (TN) * 29] : 0.0f;              \
            f32x4 aR  = {eb_r, eb_r, eb_r, eb_r};                                    \
            f32x4 aZ  = {eb_z, eb_z, eb_z, eb_z};                                    \
            f32x4 aXN = {eb_xn, eb_xn, eb_xn, eb_xn};                                \
            f32x4 aHN = {eb_hn, eb_hn, eb_hn, eb_hn};                                \
            aR  = mfma16(ax, we_xr, aR);                                             \
            aZ  = mfma16(ax, we_xz, aZ);                                             \
            aXN = mfma16(ax, we_xn, aXN);                                            \
            aR  = mfma16(ah0, we_r[0], aR);  aR  = mfma16(ah1, we_r[1], aR);         \
            aR  = mfma16(ah2, we_r[2], aR);  aR  = mfma16(ah3, we_r[3], aR);         \
            aZ  = mfma16(ah0, we_z[0], aZ);  aZ  = mfma16(ah1, we_z[1], aZ);         \
            aZ  = mfma16(ah2, we_z[2], aZ);  aZ  = mfma16(ah3, we_z[3], aZ);         \
            aHN = mfma16(ah0, we_hn[0], aHN); aHN = mfma16(ah1, we_hn[1], aHN);      \
            aHN = mfma16(ah2, we_hn[2], aHN); aHN = mfma16(ah3, we_hn[3], aHN);      \
            GATESV(OBUF);                                                            \
        } while (0)

        for (int t = 0; t < 64; t += 2) {
            ENC_STEP(0, 1, t + 1);
            ENC_STEP(1, 0, t + 2);
        }
#undef ENC_STEP
    }

    // ================= decoder =================
    float db_r, db_z, db_xn, db_hn;
    { int c = j0 + nl;
      db_r = bias[512 + c]; db_z = bias[640 + c]; db_xn = bias[768 + c]; db_hn = bias[896 + c]; }

    // step 0: xin = 0 -> gx = bih; Whh-only frags streamed once (reads h_s[0], writes h_s[1])
    {
        __syncthreads();
        f16x8 ah0 = *(const f16x8*)(&h_s[0][nl][c0]);
        f16x8 ah1 = *(const f16x8*)(&h_s[0][nl][c1]);
        f16x8 ah2 = *(const f16x8*)(&h_s[0][nl][c2]);
        f16x8 ah3 = *(const f16x8*)(&h_s[0][nl][c3]);
        int gr = j0 + nl;
        f32x4 aR  = {db_r, db_r, db_r, db_r};
        f32x4 aZ  = {db_z, db_z, db_z, db_z};
        f32x4 aHN = {db_hn, db_hn, db_hn, db_hn};
        #pragma unroll
        for (int kt = 0; kt < 4; kt++) {
            f16x8 b0 = *(const f16x8*)(dwhh + gr * 128 + kt * 32 + quad * 8);
            f16x8 b1 = *(const f16x8*)(dwhh + (128 + gr) * 128 + kt * 32 + quad * 8);
            f16x8 b2 = *(const f16x8*)(dwhh + (256 + gr) * 128 + kt * 32 + quad * 8);
            f16x8 a = (kt == 0) ? ah0 : (kt == 1) ? ah1 : (kt == 2) ? ah2 : ah3;
            aR  = mfma16(a, b0, aR);
            aZ  = mfma16(a, b1, aZ);
            aHN = mfma16(a, b2, aHN);
        }
        #pragma unroll
        for (int r = 0; r < 4; r++) {
            float ea = fexp2n(aR[r]), eb = fexp2n(aZ[r]);
            float s1 = 1.0f + ea, s2 = 1.0f + eb;
            float R = __builtin_amdgcn_rcpf(s1 * s2);
            float rg = s2 * R, zg = s1 * R;
            float ec = fexp2n(2.0f * (db_xn + rg * aHN[r]));
            float ng = (1.0f - ec) * __builtin_amdgcn_rcpf(1.0f + ec);
            float h = ng + zg * (ho[r] - ng);
            ho[r] = h;
            h_s[1][wrow + r][wcol] = (f16)h;
        }
    }
    // steps 1..63: xin == h -> combined weights
    {
        f16x8 wd_r[4], wd_z[4], wd_xn[4], wd_hn[4];
        { int gr = j0 + nl;
          #pragma unroll
          for (int kt = 0; kt < 4; kt++) {
              wd_r[kt]  = *(const f16x8*)(dwc + gr * 128 + kt * 32 + quad * 8);
              wd_z[kt]  = *(const f16x8*)(dwc + (128 + gr) * 128 + kt * 32 + quad * 8);
              wd_xn[kt] = *(const f16x8*)(dwc + (256 + gr) * 128 + kt * 32 + quad * 8);
              wd_hn[kt] = *(const f16x8*)(dwc + (384 + gr) * 128 + kt * 32 + quad * 8);
          }
        }

#define DEC_STEP(BUF, OBUF)                                                          \
        do {                                                                         \
            __syncthreads();                                                         \
            f16x8 ah0 = *(const f16x8*)(&h_s[BUF][nl][c0]);                          \
            f16x8 ah1 = *(const f16x8*)(&h_s[BUF][nl][c1]);                          \
            f16x8 ah2 = *(const f16x8*)(&h_s[BUF][nl][c2]);                          \
            f16x8 ah3 = *(const f16x8*)(&h_s[BUF][nl][c3]);                          \
            f32x4 aR  = {db_r, db_r, db_r, db_r};                                    \
            f32x4 aZ  = {db_z, db_z, db_z, db_z};                                    \
            f32x4 aXN = {db_xn, db_xn, db_xn, db_xn};                                \
            f32x4 aHN = {db_hn, db_hn, db_hn, db_hn};                                \
            aR  = mfma16(ah0, wd_r[0], aR);   aR  = mfma16(ah1, wd_r[1], aR);        \
            aR  = mfma16(ah2, wd_r[2], aR);   aR  = mfma16(ah3, wd_r[3], aR);        \
            aZ  = mfma16(ah0, wd_z[0], aZ);   aZ  = mfma16(ah1, wd_z[1], aZ);        \
            aZ  = mfma16(ah2, wd_z[2], aZ);   aZ  = mfma16(ah3, wd_z[3], aZ);        \
            aXN = mfma16(ah0, wd_xn[0], aXN); aXN = mfma16(ah1, wd_xn[1], aXN);      \
            aXN = mfma16(ah2, wd_xn[2], aXN); aXN = mfma16(ah3, wd_xn[3], aXN);      \
            aHN = mfma16(ah0, wd_hn[0], aHN); aHN = mfma16(ah1, wd_hn[1], aHN);      \
            aHN = mfma16(ah2, wd_hn[2], aHN); aHN = mfma16(ah3, wd_hn[3], aHN);      \
            GATESV(OBUF);                                                            \
        } while (0)

        DEC_STEP(1, 0);            // step 1
        for (int t = 2; t < 64; t += 2) {
            DEC_STEP(0, 1);
            DEC_STEP(1, 0);
        }
#undef DEC_STEP
#undef GATESV
    }

    // ================= heads (pn_s cols 0..127 already hold z_cnn) =================
    #pragma unroll
    for (int r = 0; r < 4; r++)
        pn_s[wrow + r][128 + j0 + nl] = ho[r];
    __syncthreads();

    const int rr = tid & 15, og = tid >> 4;   // og 0..31
    const float4* pr4 = (const float4*)(&pn_s[rr][0]);
    for (int o = og; o < 79; o += 32) {
        const float* wrow_p = (o < 78) ? (dis_w + o * 256) : value_w;
        float acc = (o < 78) ? dis_b[o] : value_b[0];
        const float4* wr4 = (const float4*)wrow_p;
        #pragma unroll 8
        for (int k = 0; k < 64; k++) {
            float4 a = wr4[k], b = pr4[k];
            acc += a.x * b.x + a.y * b.y + a.z * b.z + a.w * b.w;
        }
        if (o < 78) out[(size_t)(row0 + rr) * 78 + o] = acc;
        else        out[(size_t)8192 * 78 + row0 + rr] = acc;
    }
}

extern "C" void kernel_launch(void* const* d_in, const int* in_sizes, int n_in,
                              void* d_out, int out_size, void* d_ws, size_t ws_size,
                              hipStream_t stream)
{
    (void)in_sizes; (void)n_in; (void)out_size; (void)ws_size;
    const float* cnn  = (const float*)d_in[0];
    const float* lin  = (const float*)d_in[1];
    const float* c1w  = (const float*)d_in[2];
    const float* c1b  = (const float*)d_in[3];
    const float* c2w  = (const float*)d_in[4];
    const float* c2b  = (const float*)d_in[5];
    const float* fcw  = (const float*)d_in[6];
    const float* fcb  = (const float*)d_in[7];
    const float* eWih = (const float*)d_in[8];
    const float* eWhh = (const float*)d_in[9];
    const float* ebih = (const float*)d_in[10];
    const float* ebhh = (const float*)d_in[11];
    const float* dWih = (const float*)d_in[12];
    const float* dWhh = (const float*)d_in[13];
    const float* dbih = (const float*)d_in[14];
    const float* dbhh = (const float*)d_in[15];
    const float* disw = (const float*)d_in[16];
    const float* disb = (const float*)d_in[17];
    const float* vw   = (const float*)d_in[18];
    const float* vb   = (const float*)d_in[19];
    char* ws = (char*)d_ws;
    float* out = (float*)d_out;

    hipLaunchKernelGGL(k_prep, dim3(128), dim3(256), 0, stream,
                       eWih, eWhh, ebih, ebhh, dWih, dWhh, dbih, dbhh,
                       c1w, c2w, fcw, ws);
    hipLaunchKernelGGL(k_gru, dim3(512), dim3(512), 0, stream,
                       cnn, lin, c1b, c2b, fcb, ws, disw, disb, vw, vb, out);
}

// Round 10
// 328.819 us; speedup vs baseline: 1.0587x; 1.0045x over previous
//
#include <hip/hip_runtime.h>

typedef _Float16 f16;
typedef _Float16 f16x8 __attribute__((ext_vector_type(8)));
typedef float f32x4 __attribute__((ext_vector_type(4)));

// ---- workspace layout (bytes) ----
#define WS_EWIH 4194304                // enc Wih f16 [384][32] (k>=29 zero)
#define WS_EWHH 4218880                // enc Whh f16 [384][128]
#define WS_DWC  4317184                // dec combined f16 [512][128]
#define WS_DWHH 4448256                // dec Whh f16 [384][128]
#define WS_BIAS 4546560                // f32[1024]
#define WS_W1F  4550656                // conv1 B-frags f16 [9][16][32]
#define WS_W2F  4559872                // conv2 B-frags f16 [2][32][32]
#define WS_FCWF 4563968                // fc weights f16 [128][128]

static __device__ __forceinline__ f32x4 mfma16(f16x8 a, f16x8 b, f32x4 c) {
    return __builtin_amdgcn_mfma_f32_16x16x32_f16(a, b, c, 0, 0, 0);
}
static __device__ __forceinline__ float fexp2n(float x) {   // 2^(-x*log2e) = e^-x
    return __builtin_amdgcn_exp2f(x * -1.4426950408889634f);
}

// ---------------- prep: f32 -> f16 packs (raw values; NO scale folding) ----
__global__ void k_prep(const float* __restrict__ eWih, const float* __restrict__ eWhh,
                       const float* __restrict__ ebih, const float* __restrict__ ebhh,
                       const float* __restrict__ dWih, const float* __restrict__ dWhh,
                       const float* __restrict__ dbih, const float* __restrict__ dbhh,
                       const float* __restrict__ w1, const float* __restrict__ w2,
                       const float* __restrict__ fcw,
                       char* __restrict__ ws)
{
    f16* ewih = (f16*)(ws + WS_EWIH);
    f16* ewhh = (f16*)(ws + WS_EWHH);
    f16* dwc  = (f16*)(ws + WS_DWC);
    f16* dwhh = (f16*)(ws + WS_DWHH);
    float* bias = (float*)(ws + WS_BIAS);
    f16* w1f = (f16*)(ws + WS_W1F);
    f16* w2f = (f16*)(ws + WS_W2F);
    f16* fcwf = (f16*)(ws + WS_FCWF);
    const int total = 12288 + 49152 + 65536 + 49152 + 1024 + 4608 + 2048 + 16384;
    for (int i = blockIdx.x * 256 + threadIdx.x; i < total; i += gridDim.x * 256) {
        int j = i;
        if (j < 12288) { int g = j >> 5, k = j & 31;
            ewih[j] = (f16)((k < 29) ? eWih[g * 29 + k] : 0.0f); continue; }
        j -= 12288;
        if (j < 49152) { ewhh[j] = (f16)eWhh[j]; continue; }
        j -= 49152;
        if (j < 65536) { int row = j >> 7, k = j & 127; float v;
            if (row < 256)      v = dWih[row * 128 + k] + dWhh[row * 128 + k];
            else if (row < 384) v = dWih[row * 128 + k];
            else                v = dWhh[(row - 128) * 128 + k];
            dwc[j] = (f16)v; continue; }
        j -= 65536;
        if (j < 49152) { dwhh[j] = (f16)dWhh[j]; continue; }
        j -= 49152;
        if (j < 1024) {
            if (j < 256)        bias[j] = ebih[j] + ebhh[j];
            else if (j < 384)   bias[j] = ebih[j];
            else if (j < 512)   bias[j] = ebhh[j - 128];
            else if (j < 768)   bias[j] = dbih[j - 512] + dbhh[j - 512];
            else if (j < 896)   bias[j] = dbih[j - 512];
            else                bias[j] = dbhh[j - 640];
            continue; }
        j -= 1024;
        if (j < 4608) {   // w1f[kk][co][k]: w1 (16,27,3,3) OIHW; k>=27 -> 0
            int kk = j >> 9, rem = j & 511, co = rem >> 5, k = rem & 31;
            w1f[j] = (f16)((k < 27) ? w1[co * 243 + k * 9 + kk] : 0.0f); continue; }
        j -= 4608;
        if (j < 2048) {   // w2f[s][co][k]
            int s = j >> 10, rem = j & 1023, co = rem >> 5, k = rem & 31;
            int kk2 = 2 * s + (k >= 16), ci = k & 15;
            w2f[j] = (f16)w2[co * 64 + ci * 4 + kk2]; continue; }
        j -= 2048;
        fcwf[j] = (f16)fcw[j];
    }
}

// ---------------- fused CNN + GRU + heads: 512 threads, 16 rows/block ----------------
// R9 (best passing: k_gru 218 us) + ONE change: s_setprio(1) around each
// step's MFMA cluster (T5). Mechanism: 2 independent blocks/CU at different
// phases; priority lets MFMA-entering waves win issue arbitration over the
// other block's load/VALU waves (the attn-style regime where T5 measured
// +4-7%; the GEMM null was lockstep waves, not our case). No math change.
__global__ __launch_bounds__(512, 4) void k_gru(
    const float* __restrict__ cin,
    const float* __restrict__ lin,
    const float* __restrict__ b1, const float* __restrict__ b2,
    const float* __restrict__ fcb,
    const char* __restrict__ ws,
    const float* __restrict__ dis_w, const float* __restrict__ dis_b,
    const float* __restrict__ value_w, const float* __restrict__ value_b,
    float* __restrict__ out)
{
    __shared__ __align__(16) char smem[32000];
    f16 (*h_s)[16][136]  = (f16(*)[16][136])(smem);            // 8704 B
    f16 (*x_s)[16][32]   = (f16(*)[16][32])(smem + 8704);      // 2048 B
    float (*pn_s)[264]   = (float(*)[264])(smem + 10752);      // 16896 B
    f16 (*a1f)[9][24]    = (f16(*)[9][24])(smem);              // 6912 B, aliases h_s (CNN phase only)
    f16 (*vf)[136]       = (f16(*)[136])(smem + 27648);        // 4352 B

    const int tid = threadIdx.x;
    const int wv = tid >> 6;
    const int lane = tid & 63;
    const int nl = lane & 15;
    const int quad = lane >> 4;
    const int j0 = wv * 16;
    const int row0 = blockIdx.x * 16;

    const f16* ewih = (const f16*)(ws + WS_EWIH);
    const f16* ewhh = (const f16*)(ws + WS_EWHH);
    const f16* dwc  = (const f16*)(ws + WS_DWC);
    const f16* dwhh = (const f16*)(ws + WS_DWHH);
    const float* bias = (const float*)(ws + WS_BIAS);
    const f16* w1f = (const f16*)(ws + WS_W1F);
    const f16* w2f = (const f16*)(ws + WS_W2F);
    const f16* fcwf = (const f16*)(ws + WS_FCWF);

    // ================= CNN prologue (16 images = this block's rows) =================
    {
        const float* imgp = cin + (size_t)(row0 + nl) * 1728 + quad * 8;
        float b1v = b1[nl];
        for (int p = wv; p < 9; p += 8) {
            int oy = p / 3, ox = p % 3;
            f32x4 acc = {b1v, b1v, b1v, b1v};
            #pragma unroll
            for (int kk = 0; kk < 9; kk++) {
                f16x8 bw = *(const f16x8*)(w1f + (kk * 16 + nl) * 32 + quad * 8);
                int pix = (2 * oy + kk / 3) * 8 + (2 * ox + kk % 3);
                const float* s = imgp + pix * 27;
                f16x8 a;
                #pragma unroll
                for (int jj = 0; jj < 8; jj++) a[jj] = (f16)s[jj];
                acc = mfma16(a, bw, acc);
            }
            #pragma unroll
            for (int r = 0; r < 4; r++)
                a1f[quad * 4 + r][p][nl] = (f16)fmaxf(acc[r], 0.0f);
        }
        __syncthreads();
        // conv2: 4 positions x 2 nt = 8 units -> one per wave
        {
            int pos = wv >> 1, nt = wv & 1;
            int y = pos >> 1, x = pos & 1;
            float bv = b2[nt * 16 + nl];
            f32x4 acc = {bv, bv, bv, bv};
            #pragma unroll
            for (int s = 0; s < 2; s++) {
                int kk2 = 2 * s + (quad >> 1);
                int pos1 = (y + (kk2 >> 1)) * 3 + (x + (kk2 & 1));
                f16x8 a = *(const f16x8*)(&a1f[nl][pos1][(quad & 1) * 8]);
                f16x8 b = *(const f16x8*)(w2f + ((size_t)s * 32 + nt * 16 + nl) * 32 + quad * 8);
                acc = mfma16(a, b, acc);
            }
            #pragma unroll
            for (int r = 0; r < 4; r++)
                vf[quad * 4 + r][(nt * 16 + nl) * 4 + (y * 2 + x)] = (f16)fmaxf(acc[r], 0.0f);
        }
        __syncthreads();
        // fc 128->128: wave wv -> outputs wv*16..wv*16+15, straight into pn_s[:, 0..127]
        {
            int o = wv * 16 + nl;
            float bv = fcb[o];
            f32x4 acc = {bv, bv, bv, bv};
            #pragma unroll
            for (int kt = 0; kt < 4; kt++) {
                f16x8 a = *(const f16x8*)(&vf[nl][kt * 32 + quad * 8]);
                f16x8 b = *(const f16x8*)(fcwf + o * 128 + kt * 32 + quad * 8);
                acc = mfma16(a, b, acc);
            }
            #pragma unroll
            for (int r = 0; r < 4; r++)
                pn_s[quad * 4 + r][o] = fmaxf(acc[r], 0.0f);
        }
        __syncthreads();   // a1f dead; safe to zero h_s below
    }

    for (int i = tid; i < 2 * 16 * 136; i += 512) ((f16*)h_s)[i] = (f16)0.0f;

    const int rsw = (nl & 8) ? 16 : 0;    // read-side swizzle (row = nl)
    const int wrow = quad * 4;            // write rows wrow..wrow+3
    const int wsw = (quad >= 2) ? 16 : 0; // write-side swizzle (rows 8-15)
    const int wcol = (j0 + nl + wsw) & 127;
    const int c0 = (quad * 8 + rsw) & 127;
    const int c1 = (32 + quad * 8 + rsw) & 127;
    const int c2 = (64 + quad * 8 + rsw) & 127;
    const int c3 = (96 + quad * 8 + rsw) & 127;

    f32x4 ho = {0.0f, 0.0f, 0.0f, 0.0f};

    const int xr = tid >> 5, xc = tid & 31;   // x staging: 16 rows x 32 cols
    const bool xok = (xc < 29);
    const size_t lin_base = (size_t)(row0 + xr) * 1856 + xc;

// Vectorized gate math on f32x4 (v_pk_* packed f32); scalar only for exp2/rcp.
// Bit-identical to scalar baseline (packed = elementwise IEEE; *-2log2e fold exact).
#define GATESV(OB)                                                                   \
        do {                                                                         \
            const f32x4 onev = {1.0f, 1.0f, 1.0f, 1.0f};                             \
            f32x4 mR = aR * -1.4426950408889634f;                                    \
            f32x4 mZ = aZ * -1.4426950408889634f;                                    \
            f32x4 ea, eb;                                                            \
            _Pragma("unroll")                                                        \
            for (int r = 0; r < 4; r++) {                                            \
                ea[r] = __builtin_amdgcn_exp2f(mR[r]);                               \
                eb[r] = __builtin_amdgcn_exp2f(mZ[r]);                               \
            }                                                                        \
            f32x4 s1 = onev + ea, s2 = onev + eb;                                    \
            f32x4 pp = s1 * s2, Rv;                                                  \
            _Pragma("unroll")                                                        \
            for (int r = 0; r < 4; r++) Rv[r] = __builtin_amdgcn_rcpf(pp[r]);        \
            f32x4 rg = s2 * Rv, zg = s1 * Rv;                                        \
            f32x4 tv = (aXN + rg * aHN) * -2.8853900817779268f;                      \
            f32x4 ec;                                                                \
            _Pragma("unroll")                                                        \
            for (int r = 0; r < 4; r++) ec[r] = __builtin_amdgcn_exp2f(tv[r]);       \
            f32x4 num = onev - ec, den = onev + ec, Rd;                              \
            _Pragma("unroll")                                                        \
            for (int r = 0; r < 4; r++) Rd[r] = __builtin_amdgcn_rcpf(den[r]);       \
            f32x4 ng = num * Rd;                                                     \
            ho = ng + zg * (ho - ng);                                                \
            _Pragma("unroll")                                                        \
            for (int r = 0; r < 4; r++)                                              \
                h_s[OB][wrow + r][wcol] = (f16)ho[r];                                \
        } while (0)

    // ================= encoder =================
    {
        float eb_r, eb_z, eb_xn, eb_hn;
        { int c = j0 + nl;
          eb_r = bias[c]; eb_z = bias[128 + c]; eb_xn = bias[256 + c]; eb_hn = bias[384 + c]; }
        f16x8 we_r[4], we_z[4], we_hn[4], we_xr, we_xz, we_xn;
        { int gr = j0 + nl;
          #pragma unroll
          for (int kt = 0; kt < 4; kt++) {
              we_r[kt]  = *(const f16x8*)(ewhh + gr * 128 + kt * 32 + quad * 8);
              we_z[kt]  = *(const f16x8*)(ewhh + (128 + gr) * 128 + kt * 32 + quad * 8);
              we_hn[kt] = *(const f16x8*)(ewhh + (256 + gr) * 128 + kt * 32 + quad * 8);
          }
          we_xr = *(const f16x8*)(ewih + gr * 32 + quad * 8);
          we_xz = *(const f16x8*)(ewih + (128 + gr) * 32 + quad * 8);
          we_xn = *(const f16x8*)(ewih + (256 + gr) * 32 + quad * 8);
        }

        float xv = xok ? lin[lin_base] : 0.0f;

#define ENC_STEP(BUF, OBUF, TN)                                                      \
        do {                                                                         \
            x_s[BUF][xr][xc] = (f16)xv;                                              \
            __syncthreads();                                                         \
            f16x8 ax = *(const f16x8*)(&x_s[BUF][nl][quad * 8]);                     \
            f16x8 ah0 = *(const f16x8*)(&h_s[BUF][nl][c0]);                          \
            f16x8 ah1 = *(const f16x8*)(&h_s[BUF][nl][c1]);                          \
            f16x8 ah2 = *(const f16x8*)(&h_s[BUF][nl][c2]);                          \
            f16x8 ah3 = *(const f16x8*)(&h_s[BUF][nl][c3]);                          \
            if ((TN) < 64) xv = xok ? lin[lin_base + (TN) * 29] : 0.0f;              \
            f32x4 aR  = {eb_r, eb_r, eb_r, eb_r};                                    \
            f32x4 aZ  = {eb_z, eb_z, eb_z, eb_z};                                    \
            f32x4 aXN = {eb_xn, eb_xn, eb_xn, eb_xn};                                \
            f32x4 aHN = {eb_hn, eb_hn, eb_hn, eb_hn};                                \
            __builtin_amdgcn_s_setprio(1);                                           \
            aR  = mfma16(ax, we_xr, aR);                                             \
            aZ  = mfma16(ax, we_xz, aZ);                                             \
            aXN = mfma16(ax, we_xn, aXN);                                            \
            aR  = mfma16(ah0, we_r[0], aR);  aR  = mfma16(ah1, we_r[1], aR);         \
            aR  = mfma16(ah2, we_r[2], aR);  aR  = mfma16(ah3, we_r[3], aR);         \
            aZ  = mfma16(ah0, we_z[0], aZ);  aZ  = mfma16(ah1, we_z[1], aZ);         \
            aZ  = mfma16(ah2, we_z[2], aZ);  aZ  = mfma16(ah3, we_z[3], aZ);         \
            aHN = mfma16(ah0, we_hn[0], aHN); aHN = mfma16(ah1, we_hn[1], aHN);      \
            aHN = mfma16(ah2, we_hn[2], aHN); aHN = mfma16(ah3, we_hn[3], aHN);      \
            __builtin_amdgcn_s_setprio(0);                                           \
            GATESV(OBUF);                                                            \
        } while (0)

        for (int t = 0; t < 64; t += 2) {
            ENC_STEP(0, 1, t + 1);
            ENC_STEP(1, 0, t + 2);
        }
#undef ENC_STEP
    }

    // ================= decoder =================
    float db_r, db_z, db_xn, db_hn;
    { int c = j0 + nl;
      db_r = bias[512 + c]; db_z = bias[640 + c]; db_xn = bias[768 + c]; db_hn = bias[896 + c]; }

    // step 0: xin = 0 -> gx = bih; Whh-only frags streamed once (reads h_s[0], writes h_s[1])
    {
        __syncthreads();
        f16x8 ah0 = *(const f16x8*)(&h_s[0][nl][c0]);
        f16x8 ah1 = *(const f16x8*)(&h_s[0][nl][c1]);
        f16x8 ah2 = *(const f16x8*)(&h_s[0][nl][c2]);
        f16x8 ah3 = *(const f16x8*)(&h_s[0][nl][c3]);
        int gr = j0 + nl;
        f32x4 aR  = {db_r, db_r, db_r, db_r};
        f32x4 aZ  = {db_z, db_z, db_z, db_z};
        f32x4 aHN = {db_hn, db_hn, db_hn, db_hn};
        #pragma unroll
        for (int kt = 0; kt < 4; kt++) {
            f16x8 b0 = *(const f16x8*)(dwhh + gr * 128 + kt * 32 + quad * 8);
            f16x8 b1 = *(const f16x8*)(dwhh + (128 + gr) * 128 + kt * 32 + quad * 8);
            f16x8 b2 = *(const f16x8*)(dwhh + (256 + gr) * 128 + kt * 32 + quad * 8);
            f16x8 a = (kt == 0) ? ah0 : (kt == 1) ? ah1 : (kt == 2) ? ah2 : ah3;
            aR  = mfma16(a, b0, aR);
            aZ  = mfma16(a, b1, aZ);
            aHN = mfma16(a, b2, aHN);
        }
        #pragma unroll
        for (int r = 0; r < 4; r++) {
            float ea = fexp2n(aR[r]), eb = fexp2n(aZ[r]);
            float s1 = 1.0f + ea, s2 = 1.0f + eb;
            float R = __builtin_amdgcn_rcpf(s1 * s2);
            float rg = s2 * R, zg = s1 * R;
            float ec = fexp2n(2.0f * (db_xn + rg * aHN[r]));
            float ng = (1.0f - ec) * __builtin_amdgcn_rcpf(1.0f + ec);
            float h = ng + zg * (ho[r] - ng);
            ho[r] = h;
            h_s[1][wrow + r][wcol] = (f16)h;
        }
    }
    // steps 1..63: xin == h -> combined weights
    {
        f16x8 wd_r[4], wd_z[4], wd_xn[4], wd_hn[4];
        { int gr = j0 + nl;
          #pragma unroll
          for (int kt = 0; kt < 4; kt++) {
              wd_r[kt]  = *(const f16x8*)(dwc + gr * 128 + kt * 32 + quad * 8);
              wd_z[kt]  = *(const f16x8*)(dwc + (128 + gr) * 128 + kt * 32 + quad * 8);
              wd_xn[kt] = *(const f16x8*)(dwc + (256 + gr) * 128 + kt * 32 + quad * 8);
              wd_hn[kt] = *(const f16x8*)(dwc + (384 + gr) * 128 + kt * 32 + quad * 8);
          }
        }

#define DEC_STEP(BUF, OBUF)                                                          \
        do {                                                                         \
            __syncthreads();                                                         \
            f16x8 ah0 = *(const f16x8*)(&h_s[BUF][nl][c0]);                          \
            f16x8 ah1 = *(const f16x8*)(&h_s[BUF][nl][c1]);                          \
            f16x8 ah2 = *(const f16x8*)(&h_s[BUF][nl][c2]);                          \
            f16x8 ah3 = *(const f16x8*)(&h_s[BUF][nl][c3]);                          \
            f32x4 aR  = {db_r, db_r, db_r, db_r};                                    \
            f32x4 aZ  = {db_z, db_z, db_z, db_z};                                    \
            f32x4 aXN = {db_xn, db_xn, db_xn, db_xn};                                \
            f32x4 aHN = {db_hn, db_hn, db_hn, db_hn};                                \
            __builtin_amdgcn_s_setprio(1);                                           \
            aR  = mfma16(ah0, wd_r[0], aR);   aR  = mfma16(ah1, wd_r[1], aR);        \
            aR  = mfma16(ah2, wd_r[2], aR);   aR  = mfma16(ah3, wd_r[3], aR);        \
            aZ  = mfma16(ah0, wd_z[0], aZ);   aZ  = mfma16(ah1, wd_z[1], aZ);        \
            aZ  = mfma16(ah2, wd_z[2], aZ);   aZ  = mfma16(ah3, wd_z[3], aZ);        \
            aXN = mfma16(ah0, wd_xn[0], aXN); aXN = mfma16(ah1, wd_xn[1], aXN);      \
            aXN = mfma16(ah2, wd_xn[2], aXN); aXN = mfma16(ah3, wd_xn[3], aXN);      \
            aHN = mfma16(ah0, wd_hn[0], aHN); aHN = mfma16(ah1, wd_hn[1], aHN);      \
            aHN = mfma16(ah2, wd_hn[2], aHN); aHN = mfma16(ah3, wd_hn[3], aHN);      \
            __builtin_amdgcn_s_setprio(0);                                           \
            GATESV(OBUF);                                                            \
        } while (0)

        DEC_STEP(1, 0);            // step 1
        for (int t = 2; t < 64; t += 2) {
            DEC_STEP(0, 1);
            DEC_STEP(1, 0);
        }
#undef DEC_STEP
#undef GATESV
    }

    // ================= heads (pn_s cols 0..127 already hold z_cnn) =================
    #pragma unroll
    for (int r = 0; r < 4; r++)
        pn_s[wrow + r][128 + j0 + nl] = ho[r];
    __syncthreads();

    const int rr = tid & 15, og = tid >> 4;   // og 0..31
    const float4* pr4 = (const float4*)(&pn_s[rr][0]);
    for (int o = og; o < 79; o += 32) {
        const float* wrow_p = (o < 78) ? (dis_w + o * 256) : value_w;
        float acc = (o < 78) ? dis_b[o] : value_b[0];
        const float4* wr4 = (const float4*)wrow_p;
        #pragma unroll 8
        for (int k = 0; k < 64; k++) {
            float4 a = wr4[k], b = pr4[k];
            acc += a.x * b.x + a.y * b.y + a.z * b.z + a.w * b.w;
        }
        if (o < 78) out[(size_t)(row0 + rr) * 78 + o] = acc;
        else        out[(size_t)8192 * 78 + row0 + rr] = acc;
    }
}

extern "C" void kernel_launch(void* const* d_in, const int* in_sizes, int n_in,
                              void* d_out, int out_size, void* d_ws, size_t ws_size,
                              hipStream_t stream)
{
    (void)in_sizes; (void)n_in; (void)out_size; (void)ws_size;
    const float* cnn  = (const float*)d_in[0];
    const float* lin  = (const float*)d_in[1];
    const float* c1w  = (const float*)d_in[2];
    const float* c1b  = (const float*)d_in[3];
    const float* c2w  = (const float*)d_in[4];
    const float* c2b  = (const float*)d_in[5];
    const float* fcw  = (const float*)d_in[6];
    const float* fcb  = (const float*)d_in[7];
    const float* eWih = (const float*)d_in[8];
    const float* eWhh = (const float*)d_in[9];
    const float* ebih = (const float*)d_in[10];
    const float* ebhh = (const float*)d_in[11];
    const float* dWih = (const float*)d_in[12];
    const float* dWhh = (const float*)d_in[13];
    const float* dbih = (const float*)d_in[14];
    const float* dbhh = (const float*)d_in[15];
    const float* disw = (const float*)d_in[16];
    const float* disb = (const float*)d_in[17];
    const float* vw   = (const float*)d_in[18];
    const float* vb   = (const float*)d_in[19];
    char* ws = (char*)d_ws;
    float* out = (float*)d_out;

    hipLaunchKernelGGL(k_prep, dim3(128), dim3(256), 0, stream,
                       eWih, eWhh, ebih, ebhh, dWih, dWhh, dbih, dbhh,
                       c1w, c2w, fcw, ws);
    hipLaunchKernelGGL(k_gru, dim3(512), dim3(512), 0, stream,
                       cnn, lin, c1b, c2b, fcb, ws, disw, disb, vw, vb, out);
}